// Round 1
// baseline (344.175 us; speedup 1.0000x reference)
//
#include <hip/hip_runtime.h>

#define B_ 2
#define S_ 2048
#define HID_ 1024
#define NH_ 16
#define HD_ 64

typedef _Float16 half8 __attribute__((ext_vector_type(8)));
typedef float f32x4 __attribute__((ext_vector_type(4)));

// ---------------- prep kernels ----------------

__global__ void k_cast_f32_f16(const float* __restrict__ in, _Float16* __restrict__ out, int n) {
    int i = (blockIdx.x * blockDim.x + threadIdx.x) * 8;
    if (i >= n) return;
    float4 a = *(const float4*)&in[i];
    float4 b = *(const float4*)&in[i + 4];
    half8 h;
    h[0] = (_Float16)a.x; h[1] = (_Float16)a.y; h[2] = (_Float16)a.z; h[3] = (_Float16)a.w;
    h[4] = (_Float16)b.x; h[5] = (_Float16)b.y; h[6] = (_Float16)b.z; h[7] = (_Float16)b.w;
    *(half8*)&out[i] = h;
}

// out[n][k] = (f16) in[k][n];  in is K x N row-major
__global__ void k_transpose_cast(const float* __restrict__ in, _Float16* __restrict__ out,
                                 int K, int N) {
    __shared__ float tile[32][33];
    int n0 = blockIdx.x * 32, k0 = blockIdx.y * 32;
    int tx = threadIdx.x, ty = threadIdx.y;   // 32 x 8
    #pragma unroll
    for (int i = 0; i < 32; i += 8)
        tile[ty + i][tx] = in[(size_t)(k0 + ty + i) * N + n0 + tx];
    __syncthreads();
    #pragma unroll
    for (int i = 0; i < 32; i += 8)
        out[(size_t)(n0 + ty + i) * K + k0 + tx] = (_Float16)tile[tx][ty + i];
}

__global__ void k_rope_tables(float* __restrict__ cos_t, float* __restrict__ sin_t) {
    int s = blockIdx.x;
    int i = threadIdx.x;   // 32
    float inv = powf(10000.0f, -(float)(2 * i) / 64.0f);
    float ang = (float)s * inv;
    cos_t[s * 32 + i] = cosf(ang);
    sin_t[s * 32 + i] = sinf(ang);
}

// fused [B*S][3072] f16 -> qh,kh [b,h,s,d] with RoPE; vt [b,h,d,s]
__global__ __launch_bounds__(256) void k_reshape_rope(
        const _Float16* __restrict__ fused, const float* __restrict__ cos_t,
        const float* __restrict__ sin_t, _Float16* __restrict__ qh,
        _Float16* __restrict__ kh, _Float16* __restrict__ vt) {
    int blk = blockIdx.x;                 // B*NH*(S/64) = 1024
    int s0 = (blk & 31) * 64;
    int bh = blk >> 5;                    // b*16 + h
    int h = bh & 15;
    int t = threadIdx.x;
    int r = t >> 2, dq0 = (t & 3) * 16;   // row 0..63, d-quarter
    int s = s0 + r;
    size_t m = (size_t)(bh >> 4) * S_ + s;
    const _Float16* fr = fused + m * 3072;
    size_t qkbase = ((size_t)bh * S_ + s) * HD_;
    #pragma unroll
    for (int j = 0; j < 16; ++j) {
        int d = dq0 + j;
        int p = (d < 32) ? d + 32 : d - 32;
        float cs = cos_t[s * 32 + (d & 31)];
        float sn = sin_t[s * 32 + (d & 31)];
        float qv = (float)fr[h * 64 + d];
        float qp = (float)fr[h * 64 + p];
        qh[qkbase + d] = (_Float16)(qv * cs + ((d < 32) ? -qp : qp) * sn);
        float kv = (float)fr[1024 + h * 64 + d];
        float kp = (float)fr[1024 + h * 64 + p];
        kh[qkbase + d] = (_Float16)(kv * cs + ((d < 32) ? -kp : kp) * sn);
    }
    // V transpose through LDS
    __shared__ _Float16 vtile[64][72];
    #pragma unroll
    for (int j = 0; j < 16; ++j) {
        int d = dq0 + j;
        vtile[r][d] = fr[2048 + h * 64 + d];
    }
    __syncthreads();
    int dd = t >> 2, sc0 = (t & 3) * 16;
    size_t vbase = ((size_t)bh * HD_ + dd) * (size_t)S_ + s0 + sc0;
    #pragma unroll
    for (int j = 0; j < 16; ++j)
        vt[vbase + j] = vtile[sc0 + j][dd];
}

// ---------------- GEMM (C = A * Bt^T), f16 in, f16 or f32(+bias) out ----------------
// A: [M][K] f16 row-major, Bt: [N][K] f16 row-major.
template <bool WRITE_F32>
__global__ __launch_bounds__(256) void k_gemm(const _Float16* __restrict__ A,
                                              const _Float16* __restrict__ Bt,
                                              void* __restrict__ Cout,
                                              const float* __restrict__ bias,
                                              int M, int N, int K) {
    __shared__ _Float16 At[128 * 32];
    __shared__ _Float16 Bts[128 * 32];
    int t = threadIdx.x;
    int nb = N >> 7;
    int m0 = (blockIdx.x / nb) << 7;
    int n0 = (blockIdx.x % nb) << 7;
    int lane = t & 63, wid = t >> 6;
    int wm = (wid >> 1) * 64, wn = (wid & 1) * 64;
    int lr = lane & 15, lg = lane >> 4;
    f32x4 acc[4][4] = {};
    for (int k0 = 0; k0 < K; k0 += 32) {
        __syncthreads();
        #pragma unroll
        for (int it = 0; it < 2; ++it) {
            int idx = it * 256 + t;              // 0..511
            int row = idx >> 2, c = (idx & 3) * 8;
            *(uint4*)&At[row * 32 + c]  = *(const uint4*)&A[(size_t)(m0 + row) * K + k0 + c];
            *(uint4*)&Bts[row * 32 + c] = *(const uint4*)&Bt[(size_t)(n0 + row) * K + k0 + c];
        }
        __syncthreads();
        half8 af[4], bf[4];
        #pragma unroll
        for (int i = 0; i < 4; ++i)
            af[i] = *(const half8*)&At[(wm + i * 16 + lr) * 32 + lg * 8];
        #pragma unroll
        for (int i = 0; i < 4; ++i)
            bf[i] = *(const half8*)&Bts[(wn + i * 16 + lr) * 32 + lg * 8];
        #pragma unroll
        for (int i = 0; i < 4; ++i)
            #pragma unroll
            for (int j = 0; j < 4; ++j)
                acc[i][j] = __builtin_amdgcn_mfma_f32_16x16x32_f16(af[i], bf[j], acc[i][j], 0, 0, 0);
    }
    #pragma unroll
    for (int i = 0; i < 4; ++i) {
        #pragma unroll
        for (int j = 0; j < 4; ++j) {
            #pragma unroll
            for (int r2 = 0; r2 < 4; ++r2) {
                int row = m0 + wm + i * 16 + lg * 4 + r2;
                int col = n0 + wn + j * 16 + lr;
                float v = acc[i][j][r2];
                if constexpr (WRITE_F32)
                    ((float*)Cout)[(size_t)row * N + col] = v + bias[col];
                else
                    ((_Float16*)Cout)[(size_t)row * N + col] = (_Float16)v;
            }
        }
    }
}

// ---------------- flash attention ----------------
// qh,kh: [bh][s][d], vt: [bh][d][s], out: [b][s][h][d] f16
__global__ __launch_bounds__(256) void k_attn(const _Float16* __restrict__ qh,
                                              const _Float16* __restrict__ kh,
                                              const _Float16* __restrict__ vt,
                                              _Float16* __restrict__ attn_out) {
    int blk = blockIdx.x;                 // B*NH*(S/64) = 1024
    int qt = blk & 31;
    int bh = blk >> 5;
    int q0 = qt * 64;
    int t = threadIdx.x, lane = t & 63, w = t >> 6;
    int lr = lane & 15, lg = lane >> 4;
    const _Float16* Qb = qh + (size_t)bh * S_ * HD_;
    const _Float16* Kb = kh + (size_t)bh * S_ * HD_;
    const _Float16* Vb = vt + (size_t)bh * HD_ * S_;

    __shared__ _Float16 Kt[32][80];        // [kv][d], padded
    __shared__ _Float16 Vt[64][48];        // [d][kv], padded
    __shared__ _Float16 Pb[4][16][48];     // per-wave P tile

    int qrow = q0 + w * 16 + lr;
    half8 qf0 = *(const half8*)&Qb[(size_t)qrow * 64 + lg * 8];
    half8 qf1 = *(const half8*)&Qb[(size_t)qrow * 64 + 32 + lg * 8];

    f32x4 acc_o[4] = {};
    float mrun[4] = {-1e30f, -1e30f, -1e30f, -1e30f};
    float lrun[4] = {0.f, 0.f, 0.f, 0.f};

    int kv_end = q0 + 64;
    for (int s0 = 0; s0 < kv_end; s0 += 32) {
        __syncthreads();
        {   // stage K tile (32x64) and Vt tile (64x32)
            int row = t >> 3, c = (t & 7) * 8;
            *(uint4*)&Kt[row][c] = *(const uint4*)&Kb[(size_t)(s0 + row) * 64 + c];
            int d = t >> 2, c2 = (t & 3) * 8;
            *(uint4*)&Vt[d][c2] = *(const uint4*)&Vb[(size_t)d * S_ + s0 + c2];
        }
        __syncthreads();

        f32x4 sc[2];
        #pragma unroll
        for (int nt = 0; nt < 2; ++nt) {
            half8 kf0 = *(const half8*)&Kt[nt * 16 + lr][lg * 8];
            half8 kf1 = *(const half8*)&Kt[nt * 16 + lr][32 + lg * 8];
            f32x4 a = {0.f, 0.f, 0.f, 0.f};
            a = __builtin_amdgcn_mfma_f32_16x16x32_f16(qf0, kf0, a, 0, 0, 0);
            a = __builtin_amdgcn_mfma_f32_16x16x32_f16(qf1, kf1, a, 0, 0, 0);
            sc[nt] = a;
        }

        float fac[4];
        #pragma unroll
        for (int r2 = 0; r2 < 4; ++r2) {
            int qg = q0 + w * 16 + lg * 4 + r2;
            #pragma unroll
            for (int nt = 0; nt < 2; ++nt) {
                int kg = s0 + nt * 16 + lr;
                float v = sc[nt][r2] * 0.125f;
                sc[nt][r2] = (kg <= qg) ? v : -1e30f;
            }
            float mx = fmaxf(sc[0][r2], sc[1][r2]);
            mx = fmaxf(mx, __shfl_xor(mx, 1));
            mx = fmaxf(mx, __shfl_xor(mx, 2));
            mx = fmaxf(mx, __shfl_xor(mx, 4));
            mx = fmaxf(mx, __shfl_xor(mx, 8));
            float mnew = fmaxf(mrun[r2], mx);
            fac[r2] = __expf(mrun[r2] - mnew);
            mrun[r2] = mnew;
            float p0 = __expf(sc[0][r2] - mnew);
            float p1 = __expf(sc[1][r2] - mnew);
            sc[0][r2] = p0; sc[1][r2] = p1;
            float rs = p0 + p1;
            rs += __shfl_xor(rs, 1);
            rs += __shfl_xor(rs, 2);
            rs += __shfl_xor(rs, 4);
            rs += __shfl_xor(rs, 8);
            lrun[r2] = lrun[r2] * fac[r2] + rs;
            #pragma unroll
            for (int dt2 = 0; dt2 < 4; ++dt2) acc_o[dt2][r2] *= fac[r2];
        }

        // P -> per-wave LDS, reread as A-fragment
        #pragma unroll
        for (int nt = 0; nt < 2; ++nt)
            #pragma unroll
            for (int r2 = 0; r2 < 4; ++r2)
                Pb[w][lg * 4 + r2][nt * 16 + lr] = (_Float16)sc[nt][r2];
        asm volatile("s_waitcnt lgkmcnt(0)" ::: "memory");
        half8 pf = *(const half8*)&Pb[w][lr][lg * 8];
        #pragma unroll
        for (int dt2 = 0; dt2 < 4; ++dt2) {
            half8 vf = *(const half8*)&Vt[dt2 * 16 + lr][lg * 8];
            acc_o[dt2] = __builtin_amdgcn_mfma_f32_16x16x32_f16(pf, vf, acc_o[dt2], 0, 0, 0);
        }
    }

    int b = bh >> 4, h = bh & 15;
    #pragma unroll
    for (int r2 = 0; r2 < 4; ++r2) {
        int s = q0 + w * 16 + lg * 4 + r2;
        float inv = 1.0f / lrun[r2];
        size_t base = (((size_t)b * S_ + s) * NH_ + h) * HD_;
        #pragma unroll
        for (int dt2 = 0; dt2 < 4; ++dt2)
            attn_out[base + dt2 * 16 + lr] = (_Float16)(acc_o[dt2][r2] * inv);
    }
}

// ---------------- launch ----------------

extern "C" void kernel_launch(void* const* d_in, const int* in_sizes, int n_in,
                              void* d_out, int out_size, void* d_ws, size_t ws_size,
                              hipStream_t stream) {
    const float* hidden  = (const float*)d_in[0];
    const float* w_qkv   = (const float*)d_in[1];
    const float* w_dense = (const float*)d_in[2];
    const float* b_dense = (const float*)d_in[3];
    float* out = (float*)d_out;
    char* ws = (char*)d_ws;

    // ws layout (bytes, 16B-aligned); total ~59.2 MB
    _Float16* hh     = (_Float16*)(ws + 0);          // 8 MB  [4096][1024]; reused as qh
    _Float16* wqkvT  = (_Float16*)(ws + 8388608);    // 6 MB  [3072][1024]
    _Float16* wdT    = (_Float16*)(ws + 14680064);   // 2 MB  [1024][1024]
    float*    cos_t  = (float*)   (ws + 16777216);   // 256 KB [2048][32]
    float*    sin_t  = (float*)   (ws + 17039360);   // 256 KB
    _Float16* fused  = (_Float16*)(ws + 17301504);   // 24 MB [4096][3072]; reused as attn_out
    _Float16* kh     = (_Float16*)(ws + 42467328);   // 8 MB  [bh][s][d]
    _Float16* vt     = (_Float16*)(ws + 50855936);   // 8 MB  [bh][d][s]
    _Float16* qh     = hh;                           // alias (hh dead after QKV gemm)
    _Float16* attn_o = fused;                        // alias (fused dead after reshape)

    k_cast_f32_f16<<<2048, 256, 0, stream>>>(hidden, hh, B_ * S_ * HID_);
    k_transpose_cast<<<dim3(3 * HID_ / 32, HID_ / 32), dim3(32, 8), 0, stream>>>(w_qkv, wqkvT, HID_, 3 * HID_);
    k_transpose_cast<<<dim3(HID_ / 32, HID_ / 32), dim3(32, 8), 0, stream>>>(w_dense, wdT, HID_, HID_);
    k_rope_tables<<<S_, 32, 0, stream>>>(cos_t, sin_t);

    k_gemm<false><<<(B_ * S_ / 128) * (3 * HID_ / 128), 256, 0, stream>>>(
        hh, wqkvT, (void*)fused, nullptr, B_ * S_, 3 * HID_, HID_);

    k_reshape_rope<<<B_ * NH_ * (S_ / 64), 256, 0, stream>>>(fused, cos_t, sin_t, qh, kh, vt);

    k_attn<<<B_ * NH_ * (S_ / 64), 256, 0, stream>>>(qh, kh, vt, attn_o);

    k_gemm<true><<<(B_ * S_ / 128) * (HID_ / 128), 256, 0, stream>>>(
        attn_o, wdT, (void*)out, b_dense, B_ * S_, HID_, HID_);
}

// Round 2
// 259.180 us; speedup vs baseline: 1.3279x; 1.3279x over previous
//
#include <hip/hip_runtime.h>

#define B_ 2
#define S_ 2048
#define HID_ 1024
#define NH_ 16
#define HD_ 64

typedef _Float16 half8 __attribute__((ext_vector_type(8)));
typedef _Float16 half2_t __attribute__((ext_vector_type(2)));
typedef float f32x4 __attribute__((ext_vector_type(4)));

__device__ __forceinline__ void gload16(const _Float16* g, _Float16* l) {
    __builtin_amdgcn_global_load_lds(
        (const __attribute__((address_space(1))) void*)g,
        (__attribute__((address_space(3))) void*)l, 16, 0, 0);
}

// ---------------- prep kernels ----------------

__global__ void k_cast_f32_f16(const float* __restrict__ in, _Float16* __restrict__ out, int n) {
    int i = (blockIdx.x * blockDim.x + threadIdx.x) * 8;
    if (i >= n) return;
    float4 a = *(const float4*)&in[i];
    float4 b = *(const float4*)&in[i + 4];
    half8 h;
    h[0] = (_Float16)a.x; h[1] = (_Float16)a.y; h[2] = (_Float16)a.z; h[3] = (_Float16)a.w;
    h[4] = (_Float16)b.x; h[5] = (_Float16)b.y; h[6] = (_Float16)b.z; h[7] = (_Float16)b.w;
    *(half8*)&out[i] = h;
}

// out[n][k] = (f16) in[k][n];  in is K x N row-major
__global__ void k_transpose_cast(const float* __restrict__ in, _Float16* __restrict__ out,
                                 int K, int N) {
    __shared__ float tile[32][33];
    int n0 = blockIdx.x * 32, k0 = blockIdx.y * 32;
    int tx = threadIdx.x, ty = threadIdx.y;   // 32 x 8
    #pragma unroll
    for (int i = 0; i < 32; i += 8)
        tile[ty + i][tx] = in[(size_t)(k0 + ty + i) * N + n0 + tx];
    __syncthreads();
    #pragma unroll
    for (int i = 0; i < 32; i += 8)
        out[(size_t)(n0 + ty + i) * K + k0 + tx] = (_Float16)tile[tx][ty + i];
}

__global__ void k_rope_tables(float* __restrict__ cos_t, float* __restrict__ sin_t) {
    int s = blockIdx.x;
    int i = threadIdx.x;   // 32
    float inv = powf(10000.0f, -(float)(2 * i) / 64.0f);
    float ang = (float)s * inv;
    cos_t[s * 32 + i] = cosf(ang);
    sin_t[s * 32 + i] = sinf(ang);
}

// fused [B*S][3072] f16 -> qh,kh [b,h,s,d] with RoPE; vt [b,h,d,s]
__global__ __launch_bounds__(256) void k_reshape_rope(
        const _Float16* __restrict__ fused, const float* __restrict__ cos_t,
        const float* __restrict__ sin_t, _Float16* __restrict__ qh,
        _Float16* __restrict__ kh, _Float16* __restrict__ vt) {
    int blk = blockIdx.x;                 // B*NH*(S/64) = 1024
    int s0 = (blk & 31) * 64;
    int bh = blk >> 5;                    // b*16 + h
    int h = bh & 15;
    int t = threadIdx.x;
    int r = t >> 2, dq0 = (t & 3) * 16;   // row 0..63, d-quarter
    int s = s0 + r;
    size_t m = (size_t)(bh >> 4) * S_ + s;
    const _Float16* fr = fused + m * 3072;
    size_t qkbase = ((size_t)bh * S_ + s) * HD_;
    _Float16 qv[16], kv[16];
    #pragma unroll
    for (int j = 0; j < 16; ++j) {
        int d = dq0 + j;
        int p = (d < 32) ? d + 32 : d - 32;
        float cs = cos_t[s * 32 + (d & 31)];
        float sn = sin_t[s * 32 + (d & 31)];
        float q_ = (float)fr[h * 64 + d];
        float qp = (float)fr[h * 64 + p];
        qv[j] = (_Float16)(q_ * cs + ((d < 32) ? -qp : qp) * sn);
        float k_ = (float)fr[1024 + h * 64 + d];
        float kp = (float)fr[1024 + h * 64 + p];
        kv[j] = (_Float16)(k_ * cs + ((d < 32) ? -kp : kp) * sn);
    }
    *(half8*)&qh[qkbase + dq0]     = *(half8*)&qv[0];
    *(half8*)&qh[qkbase + dq0 + 8] = *(half8*)&qv[8];
    *(half8*)&kh[qkbase + dq0]     = *(half8*)&kv[0];
    *(half8*)&kh[qkbase + dq0 + 8] = *(half8*)&kv[8];
    // V transpose through LDS
    __shared__ _Float16 vtile[64][72];
    #pragma unroll
    for (int j = 0; j < 16; ++j)
        vtile[r][dq0 + j] = fr[2048 + h * 64 + dq0 + j];
    __syncthreads();
    int dd = t >> 2, sc0 = (t & 3) * 16;
    _Float16 vv[16];
    #pragma unroll
    for (int j = 0; j < 16; ++j)
        vv[j] = vtile[sc0 + j][dd];
    size_t vbase = ((size_t)bh * HD_ + dd) * (size_t)S_ + s0 + sc0;
    *(half8*)&vt[vbase]     = *(half8*)&vv[0];
    *(half8*)&vt[vbase + 8] = *(half8*)&vv[8];
}

// ---------------- GEMM (C = A * Bt^T), f16 in, f16 or f32(+bias) out ----------------
// A: [M][K] f16 row-major, Bt: [N][K] f16 row-major.  LDS rows padded to 40 halves.
template <bool WRITE_F32>
__global__ __launch_bounds__(256) void k_gemm(const _Float16* __restrict__ A,
                                              const _Float16* __restrict__ Bt,
                                              void* __restrict__ Cout,
                                              const float* __restrict__ bias,
                                              int M, int N, int K) {
    __shared__ _Float16 At[128 * 40];
    __shared__ _Float16 Bts[128 * 40];
    int t = threadIdx.x;
    int nb = N >> 7;
    int m0 = (blockIdx.x / nb) << 7;
    int n0 = (blockIdx.x % nb) << 7;
    int lane = t & 63, wid = t >> 6;
    int wm = (wid >> 1) * 64, wn = (wid & 1) * 64;
    int lr = lane & 15, lg = lane >> 4;
    f32x4 acc[4][4] = {};
    for (int k0 = 0; k0 < K; k0 += 32) {
        __syncthreads();
        #pragma unroll
        for (int it = 0; it < 2; ++it) {
            int idx = it * 256 + t;              // 0..511
            int row = idx >> 2, c = (idx & 3) * 8;
            *(uint4*)&At[row * 40 + c]  = *(const uint4*)&A[(size_t)(m0 + row) * K + k0 + c];
            *(uint4*)&Bts[row * 40 + c] = *(const uint4*)&Bt[(size_t)(n0 + row) * K + k0 + c];
        }
        __syncthreads();
        half8 af[4], bf[4];
        #pragma unroll
        for (int i = 0; i < 4; ++i)
            af[i] = *(const half8*)&At[(wm + i * 16 + lr) * 40 + lg * 8];
        #pragma unroll
        for (int i = 0; i < 4; ++i)
            bf[i] = *(const half8*)&Bts[(wn + i * 16 + lr) * 40 + lg * 8];
        #pragma unroll
        for (int i = 0; i < 4; ++i)
            #pragma unroll
            for (int j = 0; j < 4; ++j)
                acc[i][j] = __builtin_amdgcn_mfma_f32_16x16x32_f16(af[i], bf[j], acc[i][j], 0, 0, 0);
    }
    #pragma unroll
    for (int i = 0; i < 4; ++i) {
        #pragma unroll
        for (int j = 0; j < 4; ++j) {
            #pragma unroll
            for (int r2 = 0; r2 < 4; ++r2) {
                int row = m0 + wm + i * 16 + lg * 4 + r2;
                int col = n0 + wn + j * 16 + lr;
                float v = acc[i][j][r2];
                if constexpr (WRITE_F32)
                    ((float*)Cout)[(size_t)row * N + col] = v + bias[col];
                else
                    ((_Float16*)Cout)[(size_t)row * N + col] = (_Float16)v;
            }
        }
    }
}

// ---------------- flash attention (swapped QK^T, KVBLK=64) ----------------
// qh,kh: [bh][s][d], vt: [bh][d][s], out: [b][s][h][d] f16
__global__ __launch_bounds__(256) void k_attn(const _Float16* __restrict__ qh,
                                              const _Float16* __restrict__ kh,
                                              const _Float16* __restrict__ vt,
                                              _Float16* __restrict__ attn_out) {
    int blk = blockIdx.x;                 // B*NH*(S/64) = 1024
    int qt = 31 - (blk & 31);             // heavy blocks first
    int bh = blk >> 5;
    int q0 = qt * 64;
    int t = threadIdx.x, lane = t & 63, w = t >> 6;
    int lr = lane & 15, lg = lane >> 4;
    const _Float16* Qb = qh + (size_t)bh * S_ * HD_;
    const _Float16* Kb = kh + (size_t)bh * S_ * HD_;
    const _Float16* Vb = vt + (size_t)bh * HD_ * S_;

    __shared__ _Float16 Kt[64 * 64];      // [kv][d], chunk-swizzled
    __shared__ _Float16 Vt[64 * 64];      // [d][kv], chunk-swizzled
    __shared__ _Float16 Pl[4][16 * 64];   // per-wave [q][kv], chunk-swizzled

    int qw0 = q0 + w * 16;
    int q = qw0 + lr;
    half8 qf0 = *(const half8*)&Qb[(size_t)q * 64 + lg * 8];
    half8 qf1 = *(const half8*)&Qb[(size_t)q * 64 + 32 + lg * 8];
    const _Float16 qsc = (_Float16)0.125f;   // 1/sqrt(64), exact in f16
    #pragma unroll
    for (int j = 0; j < 8; ++j) { qf0[j] *= qsc; qf1[j] *= qsc; }

    f32x4 acc[4] = {};                    // acc[dt]: out[q=lg*4+r][d=dt*16+lr]
    float mrun = -1e30f, lrun = 0.f;
    int swq = lr & 7;

    for (int s0 = 0; s0 < q0 + 64; s0 += 64) {
        __syncthreads();
        #pragma unroll
        for (int cc = 0; cc < 2; ++cc) {
            int base = w * 128 + cc * 64;        // chunk index base (16B chunks)
            int idx = base + lane;
            int row = idx >> 3;
            int cg = (idx & 7) ^ (row & 7);      // pre-swizzled global source
            gload16(&Kb[(size_t)(s0 + row) * 64 + cg * 8], &Kt[base * 8]);
            gload16(&Vb[(size_t)row * S_ + s0 + cg * 8], &Vt[base * 8]);
        }
        __syncthreads();

        // QK^T swapped: sc[nt] = K_tile(nt) x Q^T -> C[kv][q=lr]
        f32x4 sc[4];
        #pragma unroll
        for (int nt = 0; nt < 4; ++nt) {
            int rr = nt * 16 + lr;
            int sw = rr & 7;
            half8 kf0 = *(const half8*)&Kt[rr * 64 + ((lg ^ sw) * 8)];
            half8 kf1 = *(const half8*)&Kt[rr * 64 + (((4 + lg) ^ sw) * 8)];
            f32x4 z = {0.f, 0.f, 0.f, 0.f};
            z = __builtin_amdgcn_mfma_f32_16x16x32_f16(kf0, qf0, z, 0, 0, 0);
            z = __builtin_amdgcn_mfma_f32_16x16x32_f16(kf1, qf1, z, 0, 0, 0);
            sc[nt] = z;
        }

        if (s0 + 64 > qw0) {              // causal mask needed (wave-uniform test)
            #pragma unroll
            for (int nt = 0; nt < 4; ++nt)
                #pragma unroll
                for (int r = 0; r < 4; ++r) {
                    int kv = s0 + nt * 16 + lg * 4 + r;
                    if (kv > q) sc[nt][r] = -1e30f;
                }
        }

        // online softmax: reduction over kv is in-register + 2 shfls
        float mx = sc[0][0];
        #pragma unroll
        for (int nt = 0; nt < 4; ++nt)
            #pragma unroll
            for (int r = 0; r < 4; ++r) mx = fmaxf(mx, sc[nt][r]);
        mx = fmaxf(mx, __shfl_xor(mx, 16));
        mx = fmaxf(mx, __shfl_xor(mx, 32));
        float mnew = fmaxf(mrun, mx);
        float fac = __expf(mrun - mnew);
        mrun = mnew;

        float rs = 0.f;
        #pragma unroll
        for (int nt = 0; nt < 4; ++nt)
            #pragma unroll
            for (int r = 0; r < 4; ++r) {
                float p = __expf(sc[nt][r] - mnew);
                sc[nt][r] = p;
                rs += p;
            }
        rs += __shfl_xor(rs, 16);
        rs += __shfl_xor(rs, 32);
        lrun = lrun * fac + rs;

        // rescale acc: fac for q-row lg*4+r lives in lane lr=lg*4+r
        float facv[4];
        #pragma unroll
        for (int r = 0; r < 4; ++r) facv[r] = __shfl(fac, lg * 4 + r);
        #pragma unroll
        for (int dt = 0; dt < 4; ++dt)
            #pragma unroll
            for (int r = 0; r < 4; ++r) acc[dt][r] *= facv[r];

        // pack P (f16) -> wave-local LDS [q=lr][kv], chunk-swizzled
        #pragma unroll
        for (int nt = 0; nt < 4; ++nt) {
            unsigned ua = __builtin_bit_cast(unsigned, __builtin_amdgcn_cvt_pkrtz(sc[nt][0], sc[nt][1]));
            unsigned ub = __builtin_bit_cast(unsigned, __builtin_amdgcn_cvt_pkrtz(sc[nt][2], sc[nt][3]));
            int chunk = 2 * nt + (lg >> 1);
            char* p = (char*)&Pl[w][0] + lr * 128 + ((chunk ^ swq) * 16) + (lg & 1) * 8;
            *(uint2*)p = make_uint2(ua, ub);
        }
        // wave-local: compiler orders LDS write->read via waitcnt (same object)
        half8 pa[2];
        #pragma unroll
        for (int hh = 0; hh < 2; ++hh)
            pa[hh] = *(const half8*)((const char*)&Pl[w][0] + lr * 128 + (((4 * hh + lg) ^ swq) * 16));

        #pragma unroll
        for (int dt = 0; dt < 4; ++dt) {
            int vr = dt * 16 + lr;
            #pragma unroll
            for (int hh = 0; hh < 2; ++hh) {
                half8 vb = *(const half8*)&Vt[vr * 64 + (((4 * hh + lg) ^ swq) * 8)];
                acc[dt] = __builtin_amdgcn_mfma_f32_16x16x32_f16(pa[hh], vb, acc[dt], 0, 0, 0);
            }
        }
    }

    float linv[4];
    #pragma unroll
    for (int r = 0; r < 4; ++r) linv[r] = 1.0f / __shfl(lrun, lg * 4 + r);
    int b = bh >> 4, h = bh & 15;
    #pragma unroll
    for (int dt = 0; dt < 4; ++dt)
        #pragma unroll
        for (int r = 0; r < 4; ++r) {
            int s = qw0 + lg * 4 + r;
            attn_out[((size_t)b * S_ + s) * HID_ + h * 64 + dt * 16 + lr] =
                (_Float16)(acc[dt][r] * linv[r]);
        }
}

// ---------------- launch ----------------

extern "C" void kernel_launch(void* const* d_in, const int* in_sizes, int n_in,
                              void* d_out, int out_size, void* d_ws, size_t ws_size,
                              hipStream_t stream) {
    const float* hidden  = (const float*)d_in[0];
    const float* w_qkv   = (const float*)d_in[1];
    const float* w_dense = (const float*)d_in[2];
    const float* b_dense = (const float*)d_in[3];
    float* out = (float*)d_out;
    char* ws = (char*)d_ws;

    _Float16* hh     = (_Float16*)(ws + 0);          // 8 MB  [4096][1024]; reused as qh
    _Float16* wqkvT  = (_Float16*)(ws + 8388608);    // 6 MB  [3072][1024]
    _Float16* wdT    = (_Float16*)(ws + 14680064);   // 2 MB  [1024][1024]
    float*    cos_t  = (float*)   (ws + 16777216);   // 256 KB [2048][32]
    float*    sin_t  = (float*)   (ws + 17039360);   // 256 KB
    _Float16* fused  = (_Float16*)(ws + 17301504);   // 24 MB [4096][3072]; reused as attn_out
    _Float16* kh     = (_Float16*)(ws + 42467328);   // 8 MB  [bh][s][d]
    _Float16* vt     = (_Float16*)(ws + 50855936);   // 8 MB  [bh][d][s]
    _Float16* qh     = hh;
    _Float16* attn_o = fused;

    k_cast_f32_f16<<<2048, 256, 0, stream>>>(hidden, hh, B_ * S_ * HID_);
    k_transpose_cast<<<dim3(3 * HID_ / 32, HID_ / 32), dim3(32, 8), 0, stream>>>(w_qkv, wqkvT, HID_, 3 * HID_);
    k_transpose_cast<<<dim3(HID_ / 32, HID_ / 32), dim3(32, 8), 0, stream>>>(w_dense, wdT, HID_, HID_);
    k_rope_tables<<<S_, 32, 0, stream>>>(cos_t, sin_t);

    k_gemm<false><<<(B_ * S_ / 128) * (3 * HID_ / 128), 256, 0, stream>>>(
        hh, wqkvT, (void*)fused, nullptr, B_ * S_, 3 * HID_, HID_);

    k_reshape_rope<<<B_ * NH_ * (S_ / 64), 256, 0, stream>>>(fused, cos_t, sin_t, qh, kh, vt);

    k_attn<<<B_ * NH_ * (S_ / 64), 256, 0, stream>>>(qh, kh, vt, attn_o);

    k_gemm<true><<<(B_ * S_ / 128) * (HID_ / 128), 256, 0, stream>>>(
        attn_o, wdT, (void*)out, b_dense, B_ * S_, HID_, HID_);
}

// Round 3
// 245.722 us; speedup vs baseline: 1.4007x; 1.0548x over previous
//
#include <hip/hip_runtime.h>

#define B_ 2
#define S_ 2048
#define HID_ 1024
#define NH_ 16
#define HD_ 64

typedef _Float16 half8 __attribute__((ext_vector_type(8)));
typedef float f32x4 __attribute__((ext_vector_type(4)));

__device__ __forceinline__ void gload16(const _Float16* g, _Float16* l) {
    __builtin_amdgcn_global_load_lds(
        (const __attribute__((address_space(1))) void*)g,
        (__attribute__((address_space(3))) void*)l, 16, 0, 0);
}

// ---------------- prep kernels ----------------

__global__ void k_cast_f32_f16(const float* __restrict__ in, _Float16* __restrict__ out, int n) {
    int i = (blockIdx.x * blockDim.x + threadIdx.x) * 8;
    if (i >= n) return;
    float4 a = *(const float4*)&in[i];
    float4 b = *(const float4*)&in[i + 4];
    half8 h;
    h[0] = (_Float16)a.x; h[1] = (_Float16)a.y; h[2] = (_Float16)a.z; h[3] = (_Float16)a.w;
    h[4] = (_Float16)b.x; h[5] = (_Float16)b.y; h[6] = (_Float16)b.z; h[7] = (_Float16)b.w;
    *(half8*)&out[i] = h;
}

// out[n][k] = (f16) in[k][n];  in is K x N row-major
__global__ void k_transpose_cast(const float* __restrict__ in, _Float16* __restrict__ out,
                                 int K, int N) {
    __shared__ float tile[32][33];
    int n0 = blockIdx.x * 32, k0 = blockIdx.y * 32;
    int tx = threadIdx.x, ty = threadIdx.y;   // 32 x 8
    #pragma unroll
    for (int i = 0; i < 32; i += 8)
        tile[ty + i][tx] = in[(size_t)(k0 + ty + i) * N + n0 + tx];
    __syncthreads();
    #pragma unroll
    for (int i = 0; i < 32; i += 8)
        out[(size_t)(n0 + ty + i) * K + k0 + tx] = (_Float16)tile[tx][ty + i];
}

__global__ void k_rope_tables(float* __restrict__ cos_t, float* __restrict__ sin_t) {
    int s = blockIdx.x;
    int i = threadIdx.x;   // 32
    float inv = powf(10000.0f, -(float)(2 * i) / 64.0f);
    float ang = (float)s * inv;
    cos_t[s * 32 + i] = cosf(ang);
    sin_t[s * 32 + i] = sinf(ang);
}

// fused [B*S][3072] f16 -> qh,kh [b,h,s,d] with RoPE; vt [b,h,d,s]
__global__ __launch_bounds__(256) void k_reshape_rope(
        const _Float16* __restrict__ fused, const float* __restrict__ cos_t,
        const float* __restrict__ sin_t, _Float16* __restrict__ qh,
        _Float16* __restrict__ kh, _Float16* __restrict__ vt) {
    int blk = blockIdx.x;                 // B*NH*(S/64) = 1024
    int s0 = (blk & 31) * 64;
    int bh = blk >> 5;                    // b*16 + h
    int h = bh & 15;
    int t = threadIdx.x;
    int r = t >> 2, dq0 = (t & 3) * 16;   // row 0..63, d-quarter
    int s = s0 + r;
    size_t m = (size_t)(bh >> 4) * S_ + s;
    const _Float16* fr = fused + m * 3072;
    size_t qkbase = ((size_t)bh * S_ + s) * HD_;
    _Float16 qv[16], kv[16];
    #pragma unroll
    for (int j = 0; j < 16; ++j) {
        int d = dq0 + j;
        int p = (d < 32) ? d + 32 : d - 32;
        float cs = cos_t[s * 32 + (d & 31)];
        float sn = sin_t[s * 32 + (d & 31)];
        float q_ = (float)fr[h * 64 + d];
        float qp = (float)fr[h * 64 + p];
        qv[j] = (_Float16)(q_ * cs + ((d < 32) ? -qp : qp) * sn);
        float k_ = (float)fr[1024 + h * 64 + d];
        float kp = (float)fr[1024 + h * 64 + p];
        kv[j] = (_Float16)(k_ * cs + ((d < 32) ? -kp : kp) * sn);
    }
    *(half8*)&qh[qkbase + dq0]     = *(half8*)&qv[0];
    *(half8*)&qh[qkbase + dq0 + 8] = *(half8*)&qv[8];
    *(half8*)&kh[qkbase + dq0]     = *(half8*)&kv[0];
    *(half8*)&kh[qkbase + dq0 + 8] = *(half8*)&kv[8];
    // V transpose through LDS
    __shared__ _Float16 vtile[64][72];
    #pragma unroll
    for (int j = 0; j < 16; ++j)
        vtile[r][dq0 + j] = fr[2048 + h * 64 + dq0 + j];
    __syncthreads();
    int dd = t >> 2, sc0 = (t & 3) * 16;
    _Float16 vv[16];
    #pragma unroll
    for (int j = 0; j < 16; ++j)
        vv[j] = vtile[sc0 + j][dd];
    size_t vbase = ((size_t)bh * HD_ + dd) * (size_t)S_ + s0 + sc0;
    *(half8*)&vt[vbase]     = *(half8*)&vv[0];
    *(half8*)&vt[vbase + 8] = *(half8*)&vv[8];
}

// ---------------- GEMM (C = A * Bt^T), global_load_lds staging, linear LDS ----------------
// A: [M][K] f16 row-major, Bt: [N][K] f16 row-major.
template <bool WRITE_F32>
__global__ __launch_bounds__(256) void k_gemm(const _Float16* __restrict__ A,
                                              const _Float16* __restrict__ Bt,
                                              void* __restrict__ Cout,
                                              const float* __restrict__ bias,
                                              int M, int N, int K) {
    __shared__ _Float16 At[128 * 32];
    __shared__ _Float16 Bts[128 * 32];
    int t = threadIdx.x;
    int nb = N >> 7;
    int nwg = (M >> 7) * nb;
    int bid = blockIdx.x;
    int swz = (bid & 7) * (nwg >> 3) + (bid >> 3);   // XCD-contiguous (nwg % 8 == 0)
    int m0 = (swz / nb) << 7;
    int n0 = (swz % nb) << 7;
    int lane = t & 63, wid = t >> 6;
    int wm = (wid >> 1) * 64, wn = (wid & 1) * 64;
    int lr = lane & 15, lg = lane >> 4;
    f32x4 acc[4][4] = {};
    for (int k0 = 0; k0 < K; k0 += 32) {
        __syncthreads();
        #pragma unroll
        for (int it = 0; it < 2; ++it) {
            int idx = it * 256 + t;              // 0..511, wave-contiguous
            int row = idx >> 2, c = (idx & 3) * 8;
            gload16(&A[(size_t)(m0 + row) * K + k0 + c], &At[idx * 8]);
            gload16(&Bt[(size_t)(n0 + row) * K + k0 + c], &Bts[idx * 8]);
        }
        __syncthreads();
        half8 af[4], bf[4];
        #pragma unroll
        for (int i = 0; i < 4; ++i)
            af[i] = *(const half8*)&At[(wm + i * 16 + lr) * 32 + lg * 8];
        #pragma unroll
        for (int i = 0; i < 4; ++i)
            bf[i] = *(const half8*)&Bts[(wn + i * 16 + lr) * 32 + lg * 8];
        #pragma unroll
        for (int i = 0; i < 4; ++i)
            #pragma unroll
            for (int j = 0; j < 4; ++j)
                acc[i][j] = __builtin_amdgcn_mfma_f32_16x16x32_f16(af[i], bf[j], acc[i][j], 0, 0, 0);
    }
    #pragma unroll
    for (int i = 0; i < 4; ++i) {
        #pragma unroll
        for (int j = 0; j < 4; ++j) {
            #pragma unroll
            for (int r2 = 0; r2 < 4; ++r2) {
                int row = m0 + wm + i * 16 + lg * 4 + r2;
                int col = n0 + wn + j * 16 + lr;
                float v = acc[i][j][r2];
                if constexpr (WRITE_F32)
                    ((float*)Cout)[(size_t)row * N + col] = v + bias[col];
                else
                    ((_Float16*)Cout)[(size_t)row * N + col] = (_Float16)v;
            }
        }
    }
}

// ---------------- flash attention (swapped QK^T, KVBLK=64, dbuf async stage) ----------------
// qh,kh: [bh][s][d], vt: [bh][d][s], out: [b][s][h][d] f16
__global__ __launch_bounds__(256) void k_attn(const _Float16* __restrict__ qh,
                                              const _Float16* __restrict__ kh,
                                              const _Float16* __restrict__ vt,
                                              _Float16* __restrict__ attn_out) {
    int blk0 = blockIdx.x;                // 1024 blocks
    int blk = (blk0 & 7) * 128 + (blk0 >> 3);   // XCD swizzle: same-bh blocks on one XCD
    int qt = 31 - (blk & 31);             // heavy blocks first
    int bh = blk >> 5;
    int q0 = qt * 64;
    int t = threadIdx.x, lane = t & 63, w = t >> 6;
    int lr = lane & 15, lg = lane >> 4;
    const _Float16* Qb = qh + (size_t)bh * S_ * HD_;
    const _Float16* Kb = kh + (size_t)bh * S_ * HD_;
    const _Float16* Vb = vt + (size_t)bh * HD_ * S_;

    __shared__ _Float16 Kt[2][64 * 64];   // [kv][d], chunk-swizzled
    __shared__ _Float16 Vt[2][64 * 64];   // [d][kv], chunk-swizzled
    __shared__ _Float16 Pl[4][16 * 64];   // per-wave [q][kv], chunk-swizzled

    int qw0 = q0 + w * 16;
    int q = qw0 + lr;
    half8 qf0 = *(const half8*)&Qb[(size_t)q * 64 + lg * 8];
    half8 qf1 = *(const half8*)&Qb[(size_t)q * 64 + 32 + lg * 8];
    const _Float16 qsc = (_Float16)0.125f;   // 1/sqrt(64)
    #pragma unroll
    for (int j = 0; j < 8; ++j) { qf0[j] *= qsc; qf1[j] *= qsc; }

    f32x4 acc[4] = {};                    // acc[dt]: out[q=lg*4+r][d=dt*16+lr]
    float mrun = -1e30f, lrun = 0.f;
    int swq = lr & 7;

    auto STAGE = [&](int bsel, int s0s) {
        #pragma unroll
        for (int cc = 0; cc < 2; ++cc) {
            int base = w * 128 + cc * 64;        // 16B-chunk index base
            int idx = base + lane;
            int row = idx >> 3;
            int cg = (idx & 7) ^ (row & 7);      // pre-swizzled global source
            gload16(&Kb[(size_t)(s0s + row) * 64 + cg * 8], &Kt[bsel][base * 8]);
            gload16(&Vb[(size_t)row * S_ + s0s + cg * 8], &Vt[bsel][base * 8]);
        }
    };

    int ntiles = qt + 1;
    STAGE(0, 0);                          // prologue issue
    for (int ti = 0; ti < ntiles; ++ti) {
        int s0 = ti << 6;
        int cur = ti & 1;
        __syncthreads();                  // drains vmcnt -> tile ti resident
        if (ti + 1 < ntiles) STAGE(cur ^ 1, s0 + 64);   // async prefetch under compute

        // QK^T swapped: sc[nt] = K_tile(nt) x Q^T -> C[kv][q=lr]
        f32x4 sc[4];
        #pragma unroll
        for (int nt = 0; nt < 4; ++nt) {
            int rr = nt * 16 + lr;
            int sw = rr & 7;
            half8 kf0 = *(const half8*)&Kt[cur][rr * 64 + ((lg ^ sw) * 8)];
            half8 kf1 = *(const half8*)&Kt[cur][rr * 64 + (((4 + lg) ^ sw) * 8)];
            f32x4 z = {0.f, 0.f, 0.f, 0.f};
            z = __builtin_amdgcn_mfma_f32_16x16x32_f16(kf0, qf0, z, 0, 0, 0);
            z = __builtin_amdgcn_mfma_f32_16x16x32_f16(kf1, qf1, z, 0, 0, 0);
            sc[nt] = z;
        }

        if (s0 + 64 > qw0) {              // causal mask (wave-uniform test)
            #pragma unroll
            for (int nt = 0; nt < 4; ++nt)
                #pragma unroll
                for (int r = 0; r < 4; ++r) {
                    int kv = s0 + nt * 16 + lg * 4 + r;
                    if (kv > q) sc[nt][r] = -1e30f;
                }
        }

        // tile max (per q=lr): in-register + 2 shfls
        float mx = sc[0][0];
        #pragma unroll
        for (int nt = 0; nt < 4; ++nt)
            #pragma unroll
            for (int r = 0; r < 4; ++r) mx = fmaxf(mx, sc[nt][r]);
        mx = fmaxf(mx, __shfl_xor(mx, 16));
        mx = fmaxf(mx, __shfl_xor(mx, 32));

        // defer-max: only rescale when the running max grew by > 8
        if (!__all(mx <= mrun + 8.f)) {
            float mnew = fmaxf(mrun, mx);
            float fac = __expf(mrun - mnew);
            mrun = mnew;
            lrun *= fac;
            float facv[4];
            #pragma unroll
            for (int r = 0; r < 4; ++r) facv[r] = __shfl(fac, lg * 4 + r);
            #pragma unroll
            for (int dt = 0; dt < 4; ++dt)
                #pragma unroll
                for (int r = 0; r < 4; ++r) acc[dt][r] *= facv[r];
        }

        float rs = 0.f;
        #pragma unroll
        for (int nt = 0; nt < 4; ++nt)
            #pragma unroll
            for (int r = 0; r < 4; ++r) {
                float p = __expf(sc[nt][r] - mrun);
                sc[nt][r] = p;
                rs += p;
            }
        rs += __shfl_xor(rs, 16);
        rs += __shfl_xor(rs, 32);
        lrun += rs;

        // pack P (f16) -> wave-local LDS [q=lr][kv], chunk-swizzled
        #pragma unroll
        for (int nt = 0; nt < 4; ++nt) {
            unsigned ua = __builtin_bit_cast(unsigned, __builtin_amdgcn_cvt_pkrtz(sc[nt][0], sc[nt][1]));
            unsigned ub = __builtin_bit_cast(unsigned, __builtin_amdgcn_cvt_pkrtz(sc[nt][2], sc[nt][3]));
            int chunk = 2 * nt + (lg >> 1);
            char* p = (char*)&Pl[w][0] + lr * 128 + ((chunk ^ swq) * 16) + (lg & 1) * 8;
            *(uint2*)p = make_uint2(ua, ub);
        }
        half8 pa[2];
        #pragma unroll
        for (int hh = 0; hh < 2; ++hh)
            pa[hh] = *(const half8*)((const char*)&Pl[w][0] + lr * 128 + (((4 * hh + lg) ^ swq) * 16));

        #pragma unroll
        for (int dt = 0; dt < 4; ++dt) {
            int vr = dt * 16 + lr;
            #pragma unroll
            for (int hh = 0; hh < 2; ++hh) {
                half8 vb = *(const half8*)&Vt[cur][vr * 64 + (((4 * hh + lg) ^ swq) * 8)];
                acc[dt] = __builtin_amdgcn_mfma_f32_16x16x32_f16(pa[hh], vb, acc[dt], 0, 0, 0);
            }
        }
    }

    float linv[4];
    #pragma unroll
    for (int r = 0; r < 4; ++r) linv[r] = 1.0f / __shfl(lrun, lg * 4 + r);
    int b = bh >> 4, h = bh & 15;
    #pragma unroll
    for (int dt = 0; dt < 4; ++dt)
        #pragma unroll
        for (int r = 0; r < 4; ++r) {
            int s = qw0 + lg * 4 + r;
            attn_out[((size_t)b * S_ + s) * HID_ + h * 64 + dt * 16 + lr] =
                (_Float16)(acc[dt][r] * linv[r]);
        }
}

// ---------------- launch ----------------

extern "C" void kernel_launch(void* const* d_in, const int* in_sizes, int n_in,
                              void* d_out, int out_size, void* d_ws, size_t ws_size,
                              hipStream_t stream) {
    const float* hidden  = (const float*)d_in[0];
    const float* w_qkv   = (const float*)d_in[1];
    const float* w_dense = (const float*)d_in[2];
    const float* b_dense = (const float*)d_in[3];
    float* out = (float*)d_out;
    char* ws = (char*)d_ws;

    _Float16* hh     = (_Float16*)(ws + 0);          // 8 MB  [4096][1024]; reused as qh
    _Float16* wqkvT  = (_Float16*)(ws + 8388608);    // 6 MB  [3072][1024]
    _Float16* wdT    = (_Float16*)(ws + 14680064);   // 2 MB  [1024][1024]
    float*    cos_t  = (float*)   (ws + 16777216);   // 256 KB [2048][32]
    float*    sin_t  = (float*)   (ws + 17039360);   // 256 KB
    _Float16* fused  = (_Float16*)(ws + 17301504);   // 24 MB [4096][3072]; reused as attn_out
    _Float16* kh     = (_Float16*)(ws + 42467328);   // 8 MB  [bh][s][d]
    _Float16* vt     = (_Float16*)(ws + 50855936);   // 8 MB  [bh][d][s]
    _Float16* qh     = hh;
    _Float16* attn_o = fused;

    k_cast_f32_f16<<<2048, 256, 0, stream>>>(hidden, hh, B_ * S_ * HID_);
    k_transpose_cast<<<dim3(3 * HID_ / 32, HID_ / 32), dim3(32, 8), 0, stream>>>(w_qkv, wqkvT, HID_, 3 * HID_);
    k_transpose_cast<<<dim3(HID_ / 32, HID_ / 32), dim3(32, 8), 0, stream>>>(w_dense, wdT, HID_, HID_);
    k_rope_tables<<<S_, 32, 0, stream>>>(cos_t, sin_t);

    k_gemm<false><<<(B_ * S_ / 128) * (3 * HID_ / 128), 256, 0, stream>>>(
        hh, wqkvT, (void*)fused, nullptr, B_ * S_, 3 * HID_, HID_);

    k_reshape_rope<<<B_ * NH_ * (S_ / 64), 256, 0, stream>>>(fused, cos_t, sin_t, qh, kh, vt);

    k_attn<<<B_ * NH_ * (S_ / 64), 256, 0, stream>>>(qh, kh, vt, attn_o);

    k_gemm<true><<<(B_ * S_ / 128) * (HID_ / 128), 256, 0, stream>>>(
        attn_o, wdT, (void*)out, b_dense, B_ * S_, HID_, HID_);
}

// Round 4
// 225.344 us; speedup vs baseline: 1.5273x; 1.0904x over previous
//
#include <hip/hip_runtime.h>

#define B_ 2
#define S_ 2048
#define HID_ 1024
#define NH_ 16
#define HD_ 64

typedef _Float16 half8 __attribute__((ext_vector_type(8)));
typedef float f32x4 __attribute__((ext_vector_type(4)));

__device__ __forceinline__ void gload16(const _Float16* g, _Float16* l) {
    __builtin_amdgcn_global_load_lds(
        (const __attribute__((address_space(1))) void*)g,
        (__attribute__((address_space(3))) void*)l, 16, 0, 0);
}

// ---------------- prep kernels ----------------

__global__ void k_cast_f32_f16(const float* __restrict__ in, _Float16* __restrict__ out, int n) {
    int i = (blockIdx.x * blockDim.x + threadIdx.x) * 8;
    if (i >= n) return;
    float4 a = *(const float4*)&in[i];
    float4 b = *(const float4*)&in[i + 4];
    half8 h;
    h[0] = (_Float16)a.x; h[1] = (_Float16)a.y; h[2] = (_Float16)a.z; h[3] = (_Float16)a.w;
    h[4] = (_Float16)b.x; h[5] = (_Float16)b.y; h[6] = (_Float16)b.z; h[7] = (_Float16)b.w;
    *(half8*)&out[i] = h;
}

// out[n][k] = (f16) in[k][n];  in is K x N row-major
__global__ void k_transpose_cast(const float* __restrict__ in, _Float16* __restrict__ out,
                                 int K, int N) {
    __shared__ float tile[32][33];
    int n0 = blockIdx.x * 32, k0 = blockIdx.y * 32;
    int tx = threadIdx.x, ty = threadIdx.y;   // 32 x 8
    #pragma unroll
    for (int i = 0; i < 32; i += 8)
        tile[ty + i][tx] = in[(size_t)(k0 + ty + i) * N + n0 + tx];
    __syncthreads();
    #pragma unroll
    for (int i = 0; i < 32; i += 8)
        out[(size_t)(n0 + ty + i) * K + k0 + tx] = (_Float16)tile[tx][ty + i];
}

__global__ void k_rope_tables(float* __restrict__ cos_t, float* __restrict__ sin_t) {
    int s = blockIdx.x;
    int i = threadIdx.x;   // 32
    float inv = powf(10000.0f, -(float)(2 * i) / 64.0f);
    float ang = (float)s * inv;
    cos_t[s * 32 + i] = cosf(ang);
    sin_t[s * 32 + i] = sinf(ang);
}

// fused [B*S][3072] f16 -> qh,kh [b,h,s,d] with RoPE; vt [b,h,d,s]
__global__ __launch_bounds__(256) void k_reshape_rope(
        const _Float16* __restrict__ fused, const float* __restrict__ cos_t,
        const float* __restrict__ sin_t, _Float16* __restrict__ qh,
        _Float16* __restrict__ kh, _Float16* __restrict__ vt) {
    int blk = blockIdx.x;                 // B*NH*(S/64) = 1024
    int s0 = (blk & 31) * 64;
    int bh = blk >> 5;                    // b*16 + h
    int h = bh & 15;
    int t = threadIdx.x;
    int r = t >> 2, dq0 = (t & 3) * 16;   // row 0..63, d-quarter
    int s = s0 + r;
    const _Float16* fr = fused + ((size_t)(bh >> 4) * S_ + s) * 3072;
    size_t qkbase = ((size_t)bh * S_ + s) * HD_;
    int pq0 = dq0 ^ 32;
    float sgn = (dq0 < 32) ? -1.f : 1.f;

    half8 qm[2], qp[2], km[2], kp[2], vm[2];
    qm[0] = *(const half8*)&fr[h * 64 + dq0];
    qm[1] = *(const half8*)&fr[h * 64 + dq0 + 8];
    qp[0] = *(const half8*)&fr[h * 64 + pq0];
    qp[1] = *(const half8*)&fr[h * 64 + pq0 + 8];
    km[0] = *(const half8*)&fr[1024 + h * 64 + dq0];
    km[1] = *(const half8*)&fr[1024 + h * 64 + dq0 + 8];
    kp[0] = *(const half8*)&fr[1024 + h * 64 + pq0];
    kp[1] = *(const half8*)&fr[1024 + h * 64 + pq0 + 8];
    vm[0] = *(const half8*)&fr[2048 + h * 64 + dq0];
    vm[1] = *(const half8*)&fr[2048 + h * 64 + dq0 + 8];

    const float* cb = &cos_t[s * 32 + (dq0 & 31)];
    const float* sb = &sin_t[s * 32 + (dq0 & 31)];
    half8 qo[2], ko[2];
    #pragma unroll
    for (int v8 = 0; v8 < 2; ++v8)
        #pragma unroll
        for (int j = 0; j < 8; ++j) {
            float cs = cb[v8 * 8 + j], sn = sb[v8 * 8 + j];
            qo[v8][j] = (_Float16)((float)qm[v8][j] * cs + sgn * (float)qp[v8][j] * sn);
            ko[v8][j] = (_Float16)((float)km[v8][j] * cs + sgn * (float)kp[v8][j] * sn);
        }
    *(half8*)&qh[qkbase + dq0]     = qo[0];
    *(half8*)&qh[qkbase + dq0 + 8] = qo[1];
    *(half8*)&kh[qkbase + dq0]     = ko[0];
    *(half8*)&kh[qkbase + dq0 + 8] = ko[1];

    // V transpose through LDS
    __shared__ _Float16 vtile[64][80];
    *(half8*)&vtile[r][dq0]     = vm[0];
    *(half8*)&vtile[r][dq0 + 8] = vm[1];
    __syncthreads();
    int dd = t >> 2, sc0 = (t & 3) * 16;
    _Float16 vv[16];
    #pragma unroll
    for (int j = 0; j < 16; ++j)
        vv[j] = vtile[sc0 + j][dd];
    size_t vbase = ((size_t)bh * HD_ + dd) * (size_t)S_ + s0 + sc0;
    *(half8*)&vt[vbase]     = *(half8*)&vv[0];
    *(half8*)&vt[vbase + 8] = *(half8*)&vv[8];
}

// ---------------- GEMM (C = A * Bt^T), global_load_lds staging, linear LDS ----------------
template <bool WRITE_F32>
__global__ __launch_bounds__(256) void k_gemm(const _Float16* __restrict__ A,
                                              const _Float16* __restrict__ Bt,
                                              void* __restrict__ Cout,
                                              const float* __restrict__ bias,
                                              int M, int N, int K) {
    __shared__ _Float16 At[128 * 32];
    __shared__ _Float16 Bts[128 * 32];
    int t = threadIdx.x;
    int nb = N >> 7;
    int nwg = (M >> 7) * nb;
    int bid = blockIdx.x;
    int swz = (bid & 7) * (nwg >> 3) + (bid >> 3);   // XCD-contiguous (nwg % 8 == 0)
    int m0 = (swz / nb) << 7;
    int n0 = (swz % nb) << 7;
    int lane = t & 63, wid = t >> 6;
    int wm = (wid >> 1) * 64, wn = (wid & 1) * 64;
    int lr = lane & 15, lg = lane >> 4;
    f32x4 acc[4][4] = {};
    for (int k0 = 0; k0 < K; k0 += 32) {
        __syncthreads();
        #pragma unroll
        for (int it = 0; it < 2; ++it) {
            int idx = it * 256 + t;
            int row = idx >> 2, c = (idx & 3) * 8;
            gload16(&A[(size_t)(m0 + row) * K + k0 + c], &At[idx * 8]);
            gload16(&Bt[(size_t)(n0 + row) * K + k0 + c], &Bts[idx * 8]);
        }
        __syncthreads();
        half8 af[4], bf[4];
        #pragma unroll
        for (int i = 0; i < 4; ++i)
            af[i] = *(const half8*)&At[(wm + i * 16 + lr) * 32 + lg * 8];
        #pragma unroll
        for (int i = 0; i < 4; ++i)
            bf[i] = *(const half8*)&Bts[(wn + i * 16 + lr) * 32 + lg * 8];
        #pragma unroll
        for (int i = 0; i < 4; ++i)
            #pragma unroll
            for (int j = 0; j < 4; ++j)
                acc[i][j] = __builtin_amdgcn_mfma_f32_16x16x32_f16(af[i], bf[j], acc[i][j], 0, 0, 0);
    }
    #pragma unroll
    for (int i = 0; i < 4; ++i) {
        #pragma unroll
        for (int j = 0; j < 4; ++j) {
            #pragma unroll
            for (int r2 = 0; r2 < 4; ++r2) {
                int row = m0 + wm + i * 16 + lg * 4 + r2;
                int col = n0 + wn + j * 16 + lr;
                float v = acc[i][j][r2];
                if constexpr (WRITE_F32)
                    ((float*)Cout)[(size_t)row * N + col] = v + bias[col];
                else
                    ((_Float16*)Cout)[(size_t)row * N + col] = (_Float16)v;
            }
        }
    }
}

// ---------------- flash attention: 2 waves x 32 q-rows, balanced qt map ----------------
// qh,kh: [bh][s][d], vt: [bh][d][s], out: [b][s][h][d] f16
__global__ __launch_bounds__(128) void k_attn(const _Float16* __restrict__ qh,
                                              const _Float16* __restrict__ kh,
                                              const _Float16* __restrict__ vt,
                                              _Float16* __restrict__ attn_out) {
    int blk0 = blockIdx.x;                // 1024 blocks
    int x = blk0 & 7;                     // XCD
    int i = blk0 >> 3;                    // 0..127 within XCD
    int bh = x * 4 + (i >> 5);            // 4 bh per XCD (L2-local K/V)
    int pq = (i >> 1) & 15;
    int qt = (i & 1) ? (31 - pq) : pq;    // consecutive blocks: heavy+light pair
    int q0 = qt * 64;
    int t = threadIdx.x, lane = t & 63, w = t >> 6;   // 2 waves
    int lr = lane & 15, lg = lane >> 4;
    const _Float16* Qb = qh + (size_t)bh * S_ * HD_;
    const _Float16* Kb = kh + (size_t)bh * S_ * HD_;
    const _Float16* Vb = vt + (size_t)bh * HD_ * S_;

    __shared__ _Float16 Kt[2][64 * 64];   // [kv][d], chunk-swizzled
    __shared__ _Float16 Vt[2][64 * 64];   // [d][kv], chunk-swizzled
    __shared__ _Float16 Pl[2][32 * 64];   // per-wave [q][kv], chunk-swizzled

    int qw0 = q0 + w * 32;                // wave owns 32 q-rows
    const _Float16 qsc = (_Float16)0.18033688f;   // 0.125 * log2(e)
    half8 qfrag[2][2];
    #pragma unroll
    for (int qf = 0; qf < 2; ++qf)
        #pragma unroll
        for (int dh = 0; dh < 2; ++dh) {
            qfrag[qf][dh] = *(const half8*)&Qb[(size_t)(qw0 + 16 * qf + lr) * 64 + dh * 32 + lg * 8];
            #pragma unroll
            for (int j = 0; j < 8; ++j) qfrag[qf][dh][j] *= qsc;
        }

    f32x4 acc[4][2] = {};                 // [dt][qf]: out[q=16qf+4lg+r][d=dt*16+lr]
    float mrun[2] = {-1e30f, -1e30f}, lrun[2] = {0.f, 0.f};
    int swq = lr & 7;

    auto STAGE = [&](int bsel, int s0s) {
        #pragma unroll
        for (int cc = 0; cc < 4; ++cc) {
            int base = w * 256 + cc * 64;        // 16B-chunk index base (wave-uniform)
            int idx = base + lane;
            int row = idx >> 3;
            int cg = (idx & 7) ^ (row & 7);      // pre-swizzled global source
            gload16(&Kb[(size_t)(s0s + row) * 64 + cg * 8], &Kt[bsel][base * 8]);
            gload16(&Vb[(size_t)row * S_ + s0s + cg * 8], &Vt[bsel][base * 8]);
        }
    };

    int ntiles = qt + 1;
    STAGE(0, 0);
    for (int ti = 0; ti < ntiles; ++ti) {
        int s0 = ti << 6;
        int cur = ti & 1;
        __syncthreads();                  // tile ti resident
        if (ti + 1 < ntiles) STAGE(cur ^ 1, s0 + 64);

        // swapped QK^T: sc[nt][qf] = C[kv=16nt+4lg+r][q=16qf+lr]  (log2 domain)
        f32x4 sc[4][2];
        #pragma unroll
        for (int nt = 0; nt < 4; ++nt) {
            int rr = nt * 16 + lr;
            half8 kf0 = *(const half8*)&Kt[cur][rr * 64 + ((lg ^ swq) * 8)];
            half8 kf1 = *(const half8*)&Kt[cur][rr * 64 + (((4 + lg) ^ swq) * 8)];
            #pragma unroll
            for (int qf = 0; qf < 2; ++qf) {
                f32x4 z = {0.f, 0.f, 0.f, 0.f};
                z = __builtin_amdgcn_mfma_f32_16x16x32_f16(kf0, qfrag[qf][0], z, 0, 0, 0);
                z = __builtin_amdgcn_mfma_f32_16x16x32_f16(kf1, qfrag[qf][1], z, 0, 0, 0);
                sc[nt][qf] = z;
            }
        }

        if (s0 + 64 > qw0) {              // causal mask (wave-uniform test)
            #pragma unroll
            for (int nt = 0; nt < 4; ++nt)
                #pragma unroll
                for (int qf = 0; qf < 2; ++qf)
                    #pragma unroll
                    for (int r = 0; r < 4; ++r) {
                        int kv = s0 + nt * 16 + lg * 4 + r;
                        if (kv > qw0 + 16 * qf + lr) sc[nt][qf][r] = -1e30f;
                    }
        }

        // per-q max: in-register over 16 kv + 2 shfls
        float mx[2];
        #pragma unroll
        for (int qf = 0; qf < 2; ++qf) {
            float m = sc[0][qf][0];
            #pragma unroll
            for (int nt = 0; nt < 4; ++nt)
                #pragma unroll
                for (int r = 0; r < 4; ++r) m = fmaxf(m, sc[nt][qf][r]);
            m = fmaxf(m, __shfl_xor(m, 16));
            m = fmaxf(m, __shfl_xor(m, 32));
            mx[qf] = m;
        }

        // defer-max (log2 domain, THR=11 ~ ln 8)
        bool ok = (mx[0] <= mrun[0] + 11.f) && (mx[1] <= mrun[1] + 11.f);
        if (!__all(ok)) {
            #pragma unroll
            for (int qf = 0; qf < 2; ++qf) {
                float mnew = fmaxf(mrun[qf], mx[qf]);
                float fac = __builtin_amdgcn_exp2f(mrun[qf] - mnew);
                mrun[qf] = mnew;
                lrun[qf] *= fac;
                float facv[4];
                #pragma unroll
                for (int r = 0; r < 4; ++r) facv[r] = __shfl(fac, lg * 4 + r);
                #pragma unroll
                for (int dt = 0; dt < 4; ++dt)
                    #pragma unroll
                    for (int r = 0; r < 4; ++r) acc[dt][qf][r] *= facv[r];
            }
        }

        #pragma unroll
        for (int qf = 0; qf < 2; ++qf) {
            float rs = 0.f;
            #pragma unroll
            for (int nt = 0; nt < 4; ++nt)
                #pragma unroll
                for (int r = 0; r < 4; ++r) {
                    float p = __builtin_amdgcn_exp2f(sc[nt][qf][r] - mrun[qf]);
                    sc[nt][qf][r] = p;
                    rs += p;
                }
            rs += __shfl_xor(rs, 16);
            rs += __shfl_xor(rs, 32);
            lrun[qf] += rs;
        }

        // pack P (f16) -> wave-local LDS [q=16qf+lr][kv], chunk-swizzled
        #pragma unroll
        for (int qf = 0; qf < 2; ++qf)
            #pragma unroll
            for (int nt = 0; nt < 4; ++nt) {
                unsigned ua = __builtin_bit_cast(unsigned, __builtin_amdgcn_cvt_pkrtz(sc[nt][qf][0], sc[nt][qf][1]));
                unsigned ub = __builtin_bit_cast(unsigned, __builtin_amdgcn_cvt_pkrtz(sc[nt][qf][2], sc[nt][qf][3]));
                int chunk = 2 * nt + (lg >> 1);
                char* p = (char*)&Pl[w][0] + (16 * qf + lr) * 128 + ((chunk ^ swq) * 16) + (lg & 1) * 8;
                *(uint2*)p = make_uint2(ua, ub);
            }
        half8 pa[2][2];
        #pragma unroll
        for (int qf = 0; qf < 2; ++qf)
            #pragma unroll
            for (int hh = 0; hh < 2; ++hh)
                pa[qf][hh] = *(const half8*)((const char*)&Pl[w][0] + (16 * qf + lr) * 128 + (((4 * hh + lg) ^ swq) * 16));

        #pragma unroll
        for (int dt = 0; dt < 4; ++dt) {
            int vr = dt * 16 + lr;
            #pragma unroll
            for (int hh = 0; hh < 2; ++hh) {
                half8 vb = *(const half8*)&Vt[cur][vr * 64 + (((4 * hh + lg) ^ swq) * 8)];
                #pragma unroll
                for (int qf = 0; qf < 2; ++qf)
                    acc[dt][qf] = __builtin_amdgcn_mfma_f32_16x16x32_f16(pa[qf][hh], vb, acc[dt][qf], 0, 0, 0);
            }
        }
    }

    int b = bh >> 4, h = bh & 15;
    #pragma unroll
    for (int qf = 0; qf < 2; ++qf) {
        float linv[4];
        #pragma unroll
        for (int r = 0; r < 4; ++r) linv[r] = 1.0f / __shfl(lrun[qf], lg * 4 + r);
        #pragma unroll
        for (int dt = 0; dt < 4; ++dt)
            #pragma unroll
            for (int r = 0; r < 4; ++r) {
                int s = qw0 + 16 * qf + lg * 4 + r;
                attn_out[((size_t)b * S_ + s) * HID_ + h * 64 + dt * 16 + lr] =
                    (_Float16)(acc[dt][qf][r] * linv[r]);
            }
    }
}

// ---------------- launch ----------------

extern "C" void kernel_launch(void* const* d_in, const int* in_sizes, int n_in,
                              void* d_out, int out_size, void* d_ws, size_t ws_size,
                              hipStream_t stream) {
    const float* hidden  = (const float*)d_in[0];
    const float* w_qkv   = (const float*)d_in[1];
    const float* w_dense = (const float*)d_in[2];
    const float* b_dense = (const float*)d_in[3];
    float* out = (float*)d_out;
    char* ws = (char*)d_ws;

    _Float16* hh     = (_Float16*)(ws + 0);          // 8 MB; reused as qh
    _Float16* wqkvT  = (_Float16*)(ws + 8388608);    // 6 MB
    _Float16* wdT    = (_Float16*)(ws + 14680064);   // 2 MB
    float*    cos_t  = (float*)   (ws + 16777216);   // 256 KB
    float*    sin_t  = (float*)   (ws + 17039360);   // 256 KB
    _Float16* fused  = (_Float16*)(ws + 17301504);   // 24 MB; reused as attn_out
    _Float16* kh     = (_Float16*)(ws + 42467328);   // 8 MB
    _Float16* vt     = (_Float16*)(ws + 50855936);   // 8 MB
    _Float16* qh     = hh;
    _Float16* attn_o = fused;

    k_cast_f32_f16<<<2048, 256, 0, stream>>>(hidden, hh, B_ * S_ * HID_);
    k_transpose_cast<<<dim3(3 * HID_ / 32, HID_ / 32), dim3(32, 8), 0, stream>>>(w_qkv, wqkvT, HID_, 3 * HID_);
    k_transpose_cast<<<dim3(HID_ / 32, HID_ / 32), dim3(32, 8), 0, stream>>>(w_dense, wdT, HID_, HID_);
    k_rope_tables<<<S_, 32, 0, stream>>>(cos_t, sin_t);

    k_gemm<false><<<(B_ * S_ / 128) * (3 * HID_ / 128), 256, 0, stream>>>(
        hh, wqkvT, (void*)fused, nullptr, B_ * S_, 3 * HID_, HID_);

    k_reshape_rope<<<B_ * NH_ * (S_ / 64), 256, 0, stream>>>(fused, cos_t, sin_t, qh, kh, vt);

    k_attn<<<B_ * NH_ * (S_ / 64), 128, 0, stream>>>(qh, kh, vt, attn_o);

    k_gemm<true><<<(B_ * S_ / 128) * (HID_ / 128), 256, 0, stream>>>(
        attn_o, wdT, (void*)out, b_dense, B_ * S_, HID_, HID_);
}

// Round 5
// 208.619 us; speedup vs baseline: 1.6498x; 1.0802x over previous
//
#include <hip/hip_runtime.h>

#define B_ 2
#define S_ 2048
#define HID_ 1024
#define NH_ 16
#define HD_ 64

typedef _Float16 half8 __attribute__((ext_vector_type(8)));
typedef float f32x4 __attribute__((ext_vector_type(4)));

__device__ __forceinline__ void gload16(const _Float16* g, _Float16* l) {
    __builtin_amdgcn_global_load_lds(
        (const __attribute__((address_space(1))) void*)g,
        (__attribute__((address_space(3))) void*)l, 16, 0, 0);
}

// ---------------- prep kernels ----------------

__global__ void k_cast_f32_f16(const float* __restrict__ in, _Float16* __restrict__ out, int n) {
    int i = (blockIdx.x * blockDim.x + threadIdx.x) * 8;
    if (i >= n) return;
    float4 a = *(const float4*)&in[i];
    float4 b = *(const float4*)&in[i + 4];
    half8 h;
    h[0] = (_Float16)a.x; h[1] = (_Float16)a.y; h[2] = (_Float16)a.z; h[3] = (_Float16)a.w;
    h[4] = (_Float16)b.x; h[5] = (_Float16)b.y; h[6] = (_Float16)b.z; h[7] = (_Float16)b.w;
    *(half8*)&out[i] = h;
}

// out[n][k] = (f16) in[k][n];  in is K x N row-major
__global__ void k_transpose_cast(const float* __restrict__ in, _Float16* __restrict__ out,
                                 int K, int N) {
    __shared__ float tile[32][33];
    int n0 = blockIdx.x * 32, k0 = blockIdx.y * 32;
    int tx = threadIdx.x, ty = threadIdx.y;   // 32 x 8
    #pragma unroll
    for (int i = 0; i < 32; i += 8)
        tile[ty + i][tx] = in[(size_t)(k0 + ty + i) * N + n0 + tx];
    __syncthreads();
    #pragma unroll
    for (int i = 0; i < 32; i += 8)
        out[(size_t)(n0 + ty + i) * K + k0 + tx] = (_Float16)tile[tx][ty + i];
}

__global__ void k_rope_tables(float* __restrict__ cos_t, float* __restrict__ sin_t) {
    int s = blockIdx.x;
    int i = threadIdx.x;   // 32
    float inv = powf(10000.0f, -(float)(2 * i) / 64.0f);
    float ang = (float)s * inv;
    cos_t[s * 32 + i] = cosf(ang);
    sin_t[s * 32 + i] = sinf(ang);
}

// fused [B*S][3072] f16 -> qh,kh [b,h,s,d] with RoPE; vt [b,h,d,s]
__global__ __launch_bounds__(256) void k_reshape_rope(
        const _Float16* __restrict__ fused, const float* __restrict__ cos_t,
        const float* __restrict__ sin_t, _Float16* __restrict__ qh,
        _Float16* __restrict__ kh, _Float16* __restrict__ vt) {
    int blk = blockIdx.x;                 // B*NH*(S/64) = 1024
    int s0 = (blk & 31) * 64;
    int bh = blk >> 5;                    // b*16 + h
    int h = bh & 15;
    int t = threadIdx.x;
    int r = t >> 2, dq0 = (t & 3) * 16;   // row 0..63, d-quarter
    int s = s0 + r;
    const _Float16* fr = fused + ((size_t)(bh >> 4) * S_ + s) * 3072;
    size_t qkbase = ((size_t)bh * S_ + s) * HD_;
    int pq0 = dq0 ^ 32;
    float sgn = (dq0 < 32) ? -1.f : 1.f;

    half8 qm[2], qp[2], km[2], kp[2], vm[2];
    qm[0] = *(const half8*)&fr[h * 64 + dq0];
    qm[1] = *(const half8*)&fr[h * 64 + dq0 + 8];
    qp[0] = *(const half8*)&fr[h * 64 + pq0];
    qp[1] = *(const half8*)&fr[h * 64 + pq0 + 8];
    km[0] = *(const half8*)&fr[1024 + h * 64 + dq0];
    km[1] = *(const half8*)&fr[1024 + h * 64 + dq0 + 8];
    kp[0] = *(const half8*)&fr[1024 + h * 64 + pq0];
    kp[1] = *(const half8*)&fr[1024 + h * 64 + pq0 + 8];
    vm[0] = *(const half8*)&fr[2048 + h * 64 + dq0];
    vm[1] = *(const half8*)&fr[2048 + h * 64 + dq0 + 8];

    const float* cb = &cos_t[s * 32 + (dq0 & 31)];
    const float* sb = &sin_t[s * 32 + (dq0 & 31)];
    half8 qo[2], ko[2];
    #pragma unroll
    for (int v8 = 0; v8 < 2; ++v8)
        #pragma unroll
        for (int j = 0; j < 8; ++j) {
            float cs = cb[v8 * 8 + j], sn = sb[v8 * 8 + j];
            qo[v8][j] = (_Float16)((float)qm[v8][j] * cs + sgn * (float)qp[v8][j] * sn);
            ko[v8][j] = (_Float16)((float)km[v8][j] * cs + sgn * (float)kp[v8][j] * sn);
        }
    *(half8*)&qh[qkbase + dq0]     = qo[0];
    *(half8*)&qh[qkbase + dq0 + 8] = qo[1];
    *(half8*)&kh[qkbase + dq0]     = ko[0];
    *(half8*)&kh[qkbase + dq0 + 8] = ko[1];

    // V transpose through LDS
    __shared__ _Float16 vtile[64][80];
    *(half8*)&vtile[r][dq0]     = vm[0];
    *(half8*)&vtile[r][dq0 + 8] = vm[1];
    __syncthreads();
    int dd = t >> 2, sc0 = (t & 3) * 16;
    _Float16 vv[16];
    #pragma unroll
    for (int j = 0; j < 16; ++j)
        vv[j] = vtile[sc0 + j][dd];
    size_t vbase = ((size_t)bh * HD_ + dd) * (size_t)S_ + s0 + sc0;
    *(half8*)&vt[vbase]     = *(half8*)&vv[0];
    *(half8*)&vt[vbase + 8] = *(half8*)&vv[8];
}

// ---------------- GEMM (C = A * Bt^T), global_load_lds staging, linear LDS ----------------
template <bool WRITE_F32>
__global__ __launch_bounds__(256) void k_gemm(const _Float16* __restrict__ A,
                                              const _Float16* __restrict__ Bt,
                                              void* __restrict__ Cout,
                                              const float* __restrict__ bias,
                                              int M, int N, int K) {
    __shared__ _Float16 At[128 * 32];
    __shared__ _Float16 Bts[128 * 32];
    int t = threadIdx.x;
    int nb = N >> 7;
    int nwg = (M >> 7) * nb;
    int bid = blockIdx.x;
    int swz = (bid & 7) * (nwg >> 3) + (bid >> 3);   // XCD-contiguous (nwg % 8 == 0)
    int m0 = (swz / nb) << 7;
    int n0 = (swz % nb) << 7;
    int lane = t & 63, wid = t >> 6;
    int wm = (wid >> 1) * 64, wn = (wid & 1) * 64;
    int lr = lane & 15, lg = lane >> 4;
    f32x4 acc[4][4] = {};
    for (int k0 = 0; k0 < K; k0 += 32) {
        __syncthreads();
        #pragma unroll
        for (int it = 0; it < 2; ++it) {
            int idx = it * 256 + t;
            int row = idx >> 2, c = (idx & 3) * 8;
            gload16(&A[(size_t)(m0 + row) * K + k0 + c], &At[idx * 8]);
            gload16(&Bt[(size_t)(n0 + row) * K + k0 + c], &Bts[idx * 8]);
        }
        __syncthreads();
        half8 af[4], bf[4];
        #pragma unroll
        for (int i = 0; i < 4; ++i)
            af[i] = *(const half8*)&At[(wm + i * 16 + lr) * 32 + lg * 8];
        #pragma unroll
        for (int i = 0; i < 4; ++i)
            bf[i] = *(const half8*)&Bts[(wn + i * 16 + lr) * 32 + lg * 8];
        #pragma unroll
        for (int i = 0; i < 4; ++i)
            #pragma unroll
            for (int j = 0; j < 4; ++j)
                acc[i][j] = __builtin_amdgcn_mfma_f32_16x16x32_f16(af[i], bf[j], acc[i][j], 0, 0, 0);
    }
    #pragma unroll
    for (int i = 0; i < 4; ++i) {
        #pragma unroll
        for (int j = 0; j < 4; ++j) {
            #pragma unroll
            for (int r2 = 0; r2 < 4; ++r2) {
                int row = m0 + wm + i * 16 + lg * 4 + r2;
                int col = n0 + wn + j * 16 + lr;
                float v = acc[i][j][r2];
                if constexpr (WRITE_F32)
                    ((float*)Cout)[(size_t)row * N + col] = v + bias[col];
                else
                    ((_Float16*)Cout)[(size_t)row * N + col] = (_Float16)v;
            }
        }
    }
}

// ---------------- flash attention: diagonal-paired q-tiles, uniform 33 tiles/block ----------------
// 512 blocks x 4 waves x 16 q-rows. Each block handles q-tiles qtA=p and qtB=31-p
// over one shared kv sweep -> work is uniform regardless of scheduler placement.
// qh,kh: [bh][s][d], vt: [bh][d][s], out: [b][s][h][d] f16
__global__ __launch_bounds__(256) void k_attn(const _Float16* __restrict__ qh,
                                              const _Float16* __restrict__ kh,
                                              const _Float16* __restrict__ vt,
                                              _Float16* __restrict__ attn_out) {
    int blk0 = blockIdx.x;                // 512 blocks
    int x = blk0 & 7;                     // XCD
    int i = blk0 >> 3;                    // 0..63 within XCD
    int bh = x * 4 + (i >> 4);            // 4 bh per XCD (L2-local K/V)
    int p = i & 15;
    int qtA = p, qtB = 31 - p;            // qtB >= 16 > qtA
    int t = threadIdx.x, lane = t & 63, w = t >> 6;
    int lr = lane & 15, lg = lane >> 4;
    const _Float16* Qb = qh + (size_t)bh * S_ * HD_;
    const _Float16* Kb = kh + (size_t)bh * S_ * HD_;
    const _Float16* Vb = vt + (size_t)bh * HD_ * S_;

    __shared__ _Float16 Kt[2][64 * 64];   // [kv][d], chunk-swizzled
    __shared__ _Float16 Vt[2][64 * 64];   // [d][kv], chunk-swizzled
    __shared__ _Float16 Pl[4][16 * 64];   // per-wave [q][kv], chunk-swizzled

    const _Float16 qsc = (_Float16)0.18033688f;   // 0.125 * log2(e)
    half8 qfA[2], qfB[2];
    {
        int qA = qtA * 64 + w * 16 + lr;
        int qB = qtB * 64 + w * 16 + lr;
        #pragma unroll
        for (int dh = 0; dh < 2; ++dh) {
            qfA[dh] = *(const half8*)&Qb[(size_t)qA * 64 + dh * 32 + lg * 8];
            qfB[dh] = *(const half8*)&Qb[(size_t)qB * 64 + dh * 32 + lg * 8];
            #pragma unroll
            for (int j = 0; j < 8; ++j) { qfA[dh][j] *= qsc; qfB[dh][j] *= qsc; }
        }
    }

    f32x4 accA[4] = {}, accB[4] = {};
    float mA = -1e30f, lA = 0.f, mB = -1e30f, lB = 0.f;
    int swq = lr & 7;
    int s0 = 0, cur = 0;

    auto STAGE = [&](int bsel, int s0s) {
        #pragma unroll
        for (int cc = 0; cc < 2; ++cc) {
            int base = w * 128 + cc * 64;        // 16B-chunk index base (wave-uniform)
            int idx = base + lane;
            int row = idx >> 3;
            int cg = (idx & 7) ^ (row & 7);      // pre-swizzled global source
            gload16(&Kb[(size_t)(s0s + row) * 64 + cg * 8], &Kt[bsel][base * 8]);
            gload16(&Vb[(size_t)row * S_ + s0s + cg * 8], &Vt[bsel][base * 8]);
        }
    };

    // one group's full tile step: QK^T (swapped), online softmax (log2), P->LDS, PV
    auto process = [&](const half8* qf, f32x4* acc, float& mrun, float& lrun, int q0g) {
        int qw0 = q0g + w * 16;
        int q = qw0 + lr;
        f32x4 sc[4];
        #pragma unroll
        for (int nt = 0; nt < 4; ++nt) {
            int rr = nt * 16 + lr;
            half8 kf0 = *(const half8*)&Kt[cur][rr * 64 + ((lg ^ swq) * 8)];
            half8 kf1 = *(const half8*)&Kt[cur][rr * 64 + (((4 + lg) ^ swq) * 8)];
            f32x4 z = {0.f, 0.f, 0.f, 0.f};
            z = __builtin_amdgcn_mfma_f32_16x16x32_f16(kf0, qf[0], z, 0, 0, 0);
            z = __builtin_amdgcn_mfma_f32_16x16x32_f16(kf1, qf[1], z, 0, 0, 0);
            sc[nt] = z;
        }
        if (s0 + 64 > qw0) {              // causal mask (wave-uniform test)
            #pragma unroll
            for (int nt = 0; nt < 4; ++nt)
                #pragma unroll
                for (int r = 0; r < 4; ++r) {
                    int kv = s0 + nt * 16 + lg * 4 + r;
                    if (kv > q) sc[nt][r] = -1e30f;
                }
        }
        float mx = sc[0][0];
        #pragma unroll
        for (int nt = 0; nt < 4; ++nt)
            #pragma unroll
            for (int r = 0; r < 4; ++r) mx = fmaxf(mx, sc[nt][r]);
        mx = fmaxf(mx, __shfl_xor(mx, 16));
        mx = fmaxf(mx, __shfl_xor(mx, 32));

        if (!__all(mx <= mrun + 11.f)) {  // defer-max (log2 domain)
            float mnew = fmaxf(mrun, mx);
            float fac = __builtin_amdgcn_exp2f(mrun - mnew);
            mrun = mnew;
            lrun *= fac;
            float facv[4];
            #pragma unroll
            for (int r = 0; r < 4; ++r) facv[r] = __shfl(fac, lg * 4 + r);
            #pragma unroll
            for (int dt = 0; dt < 4; ++dt)
                #pragma unroll
                for (int r = 0; r < 4; ++r) acc[dt][r] *= facv[r];
        }

        float rs = 0.f;
        #pragma unroll
        for (int nt = 0; nt < 4; ++nt)
            #pragma unroll
            for (int r = 0; r < 4; ++r) {
                float pv = __builtin_amdgcn_exp2f(sc[nt][r] - mrun);
                sc[nt][r] = pv;
                rs += pv;
            }
        rs += __shfl_xor(rs, 16);
        rs += __shfl_xor(rs, 32);
        lrun += rs;

        #pragma unroll
        for (int nt = 0; nt < 4; ++nt) {
            unsigned ua = __builtin_bit_cast(unsigned, __builtin_amdgcn_cvt_pkrtz(sc[nt][0], sc[nt][1]));
            unsigned ub = __builtin_bit_cast(unsigned, __builtin_amdgcn_cvt_pkrtz(sc[nt][2], sc[nt][3]));
            int chunk = 2 * nt + (lg >> 1);
            char* pp = (char*)&Pl[w][0] + lr * 128 + ((chunk ^ swq) * 16) + (lg & 1) * 8;
            *(uint2*)pp = make_uint2(ua, ub);
        }
        half8 pa[2];
        #pragma unroll
        for (int hh = 0; hh < 2; ++hh)
            pa[hh] = *(const half8*)((const char*)&Pl[w][0] + lr * 128 + (((4 * hh + lg) ^ swq) * 16));

        #pragma unroll
        for (int dt = 0; dt < 4; ++dt) {
            int vr = dt * 16 + lr;
            #pragma unroll
            for (int hh = 0; hh < 2; ++hh) {
                half8 vb = *(const half8*)&Vt[cur][vr * 64 + (((4 * hh + lg) ^ swq) * 8)];
                acc[dt] = __builtin_amdgcn_mfma_f32_16x16x32_f16(pa[hh], vb, acc[dt], 0, 0, 0);
            }
        }
    };

    int ntiles = qtB + 1;
    STAGE(0, 0);
    for (int ti = 0; ti < ntiles; ++ti) {
        s0 = ti << 6;
        cur = ti & 1;
        __syncthreads();                  // tile ti resident
        if (ti + 1 < ntiles) STAGE(cur ^ 1, s0 + 64);
        process(qfB, accB, mB, lB, qtB * 64);
        if (ti <= qtA)
            process(qfA, accA, mA, lA, qtA * 64);
    }

    int b = bh >> 4, h = bh & 15;
    auto writeout = [&](const f32x4* acc, float lrun, int q0g) {
        float linv[4];
        #pragma unroll
        for (int r = 0; r < 4; ++r) linv[r] = 1.0f / __shfl(lrun, lg * 4 + r);
        #pragma unroll
        for (int dt = 0; dt < 4; ++dt)
            #pragma unroll
            for (int r = 0; r < 4; ++r) {
                int s = q0g + w * 16 + lg * 4 + r;
                attn_out[((size_t)b * S_ + s) * HID_ + h * 64 + dt * 16 + lr] =
                    (_Float16)(acc[dt][r] * linv[r]);
            }
    };
    writeout(accB, lB, qtB * 64);
    writeout(accA, lA, qtA * 64);
}

// ---------------- launch ----------------

extern "C" void kernel_launch(void* const* d_in, const int* in_sizes, int n_in,
                              void* d_out, int out_size, void* d_ws, size_t ws_size,
                              hipStream_t stream) {
    const float* hidden  = (const float*)d_in[0];
    const float* w_qkv   = (const float*)d_in[1];
    const float* w_dense = (const float*)d_in[2];
    const float* b_dense = (const float*)d_in[3];
    float* out = (float*)d_out;
    char* ws = (char*)d_ws;

    _Float16* hh     = (_Float16*)(ws + 0);          // 8 MB; reused as qh
    _Float16* wqkvT  = (_Float16*)(ws + 8388608);    // 6 MB
    _Float16* wdT    = (_Float16*)(ws + 14680064);   // 2 MB
    float*    cos_t  = (float*)   (ws + 16777216);   // 256 KB
    float*    sin_t  = (float*)   (ws + 17039360);   // 256 KB
    _Float16* fused  = (_Float16*)(ws + 17301504);   // 24 MB; reused as attn_out
    _Float16* kh     = (_Float16*)(ws + 42467328);   // 8 MB
    _Float16* vt     = (_Float16*)(ws + 50855936);   // 8 MB
    _Float16* qh     = hh;
    _Float16* attn_o = fused;

    k_cast_f32_f16<<<2048, 256, 0, stream>>>(hidden, hh, B_ * S_ * HID_);
    k_transpose_cast<<<dim3(3 * HID_ / 32, HID_ / 32), dim3(32, 8), 0, stream>>>(w_qkv, wqkvT, HID_, 3 * HID_);
    k_transpose_cast<<<dim3(HID_ / 32, HID_ / 32), dim3(32, 8), 0, stream>>>(w_dense, wdT, HID_, HID_);
    k_rope_tables<<<S_, 32, 0, stream>>>(cos_t, sin_t);

    k_gemm<false><<<(B_ * S_ / 128) * (3 * HID_ / 128), 256, 0, stream>>>(
        hh, wqkvT, (void*)fused, nullptr, B_ * S_, 3 * HID_, HID_);

    k_reshape_rope<<<B_ * NH_ * (S_ / 64), 256, 0, stream>>>(fused, cos_t, sin_t, qh, kh, vt);

    k_attn<<<B_ * NH_ * (S_ / 64) / 2, 256, 0, stream>>>(qh, kh, vt, attn_o);

    k_gemm<true><<<(B_ * S_ / 128) * (HID_ / 128), 256, 0, stream>>>(
        attn_o, wdT, (void*)out, b_dense, B_ * S_, HID_, HID_);
}

// Round 7
// 204.995 us; speedup vs baseline: 1.6789x; 1.0177x over previous
//
#include <hip/hip_runtime.h>

#define B_ 2
#define S_ 2048
#define HID_ 1024
#define NH_ 16
#define HD_ 64

typedef _Float16 half8 __attribute__((ext_vector_type(8)));
typedef float f32x4 __attribute__((ext_vector_type(4)));

__device__ __forceinline__ void gload16(const _Float16* g, _Float16* l) {
    __builtin_amdgcn_global_load_lds(
        (const __attribute__((address_space(1))) void*)g,
        (__attribute__((address_space(3))) void*)l, 16, 0, 0);
}

// ---------------- fused prep: cast + both weight transposes + rope tables ----------------

__device__ __forceinline__ void tr32(const float* __restrict__ in, _Float16* __restrict__ out,
                                     int K, int N, int n0, int k0, int tx, int ty,
                                     float (*tile)[33]) {
    #pragma unroll
    for (int i2 = 0; i2 < 32; i2 += 8)
        tile[ty + i2][tx] = in[(size_t)(k0 + ty + i2) * N + n0 + tx];
    __syncthreads();
    #pragma unroll
    for (int i2 = 0; i2 < 32; i2 += 8)
        out[(size_t)(n0 + ty + i2) * K + k0 + tx] = (_Float16)tile[tx][ty + i2];
}

__global__ __launch_bounds__(256) void k_prep(
        const float* __restrict__ hidden, const float* __restrict__ w_qkv,
        const float* __restrict__ w_dense, _Float16* __restrict__ hh,
        _Float16* __restrict__ wqkvT, _Float16* __restrict__ wdT,
        float* __restrict__ cos_t, float* __restrict__ sin_t) {
    int b = blockIdx.x, t = threadIdx.x;
    __shared__ float tile[32][33];
    if (b < 2048) {                        // cast hidden f32 -> f16 (8/thread)
        int i = (b * 256 + t) * 8;
        float4 a = *(const float4*)&hidden[i];
        float4 c = *(const float4*)&hidden[i + 4];
        half8 h;
        h[0] = (_Float16)a.x; h[1] = (_Float16)a.y; h[2] = (_Float16)a.z; h[3] = (_Float16)a.w;
        h[4] = (_Float16)c.x; h[5] = (_Float16)c.y; h[6] = (_Float16)c.z; h[7] = (_Float16)c.w;
        *(half8*)&hh[i] = h;
    } else if (b < 5120) {                 // w_qkv^T: 96 x 32 tiles
        int bb = b - 2048;
        tr32(w_qkv, wqkvT, HID_, 3 * HID_, (bb % 96) * 32, (bb / 96) * 32, t & 31, t >> 5, tile);
    } else if (b < 6144) {                 // w_dense^T: 32 x 32 tiles
        int bb = b - 5120;
        tr32(w_dense, wdT, HID_, HID_, (bb % 32) * 32, (bb / 32) * 32, t & 31, t >> 5, tile);
    } else {                               // rope tables: 8 rows/block
        int bb = b - 6144;
        int s = bb * 8 + (t >> 5);
        int ii = t & 31;
        float inv = powf(10000.0f, -(float)(2 * ii) / 64.0f);
        float ang = (float)s * inv;
        cos_t[s * 32 + ii] = cosf(ang);
        sin_t[s * 32 + ii] = sinf(ang);
    }
}

// fused [B*S][3072] f16 -> qh,kh [b,h,s,d] with RoPE; vt [b,h,d,s]
__global__ __launch_bounds__(256) void k_reshape_rope(
        const _Float16* __restrict__ fused, const float* __restrict__ cos_t,
        const float* __restrict__ sin_t, _Float16* __restrict__ qh,
        _Float16* __restrict__ kh, _Float16* __restrict__ vt) {
    int blk = blockIdx.x;                 // 1024
    int s0 = (blk & 31) * 64;
    int bh = blk >> 5;
    int h = bh & 15;
    int t = threadIdx.x;
    int r = t >> 2, dq0 = (t & 3) * 16;
    int s = s0 + r;
    const _Float16* fr = fused + ((size_t)(bh >> 4) * S_ + s) * 3072;
    size_t qkbase = ((size_t)bh * S_ + s) * HD_;
    int pq0 = dq0 ^ 32;
    float sgn = (dq0 < 32) ? -1.f : 1.f;

    half8 qm[2], qp[2], km[2], kp[2], vm[2];
    qm[0] = *(const half8*)&fr[h * 64 + dq0];
    qm[1] = *(const half8*)&fr[h * 64 + dq0 + 8];
    qp[0] = *(const half8*)&fr[h * 64 + pq0];
    qp[1] = *(const half8*)&fr[h * 64 + pq0 + 8];
    km[0] = *(const half8*)&fr[1024 + h * 64 + dq0];
    km[1] = *(const half8*)&fr[1024 + h * 64 + dq0 + 8];
    kp[0] = *(const half8*)&fr[1024 + h * 64 + pq0];
    kp[1] = *(const half8*)&fr[1024 + h * 64 + pq0 + 8];
    vm[0] = *(const half8*)&fr[2048 + h * 64 + dq0];
    vm[1] = *(const half8*)&fr[2048 + h * 64 + dq0 + 8];

    const float* cb = &cos_t[s * 32 + (dq0 & 31)];
    const float* sb = &sin_t[s * 32 + (dq0 & 31)];
    half8 qo[2], ko[2];
    #pragma unroll
    for (int v8 = 0; v8 < 2; ++v8)
        #pragma unroll
        for (int j = 0; j < 8; ++j) {
            float cs = cb[v8 * 8 + j], sn = sb[v8 * 8 + j];
            qo[v8][j] = (_Float16)((float)qm[v8][j] * cs + sgn * (float)qp[v8][j] * sn);
            ko[v8][j] = (_Float16)((float)km[v8][j] * cs + sgn * (float)kp[v8][j] * sn);
        }
    *(half8*)&qh[qkbase + dq0]     = qo[0];
    *(half8*)&qh[qkbase + dq0 + 8] = qo[1];
    *(half8*)&kh[qkbase + dq0]     = ko[0];
    *(half8*)&kh[qkbase + dq0 + 8] = ko[1];

    __shared__ _Float16 vtile[64][80];
    *(half8*)&vtile[r][dq0]     = vm[0];
    *(half8*)&vtile[r][dq0 + 8] = vm[1];
    __syncthreads();
    int dd = t >> 2, sc0 = (t & 3) * 16;
    _Float16 vv[16];
    #pragma unroll
    for (int j = 0; j < 16; ++j)
        vv[j] = vtile[sc0 + j][dd];
    size_t vbase = ((size_t)bh * HD_ + dd) * (size_t)S_ + s0 + sc0;
    *(half8*)&vt[vbase]     = *(half8*)&vv[0];
    *(half8*)&vt[vbase + 8] = *(half8*)&vv[8];
}

// ---------------- GEMM (C = A * Bt^T), global_load_lds staging, linear LDS ----------------
template <bool WRITE_F32>
__global__ __launch_bounds__(256) void k_gemm(const _Float16* __restrict__ A,
                                              const _Float16* __restrict__ Bt,
                                              void* __restrict__ Cout,
                                              const float* __restrict__ bias,
                                              int M, int N, int K) {
    __shared__ _Float16 At[128 * 32];
    __shared__ _Float16 Bts[128 * 32];
    int t = threadIdx.x;
    int nb = N >> 7;
    int nwg = (M >> 7) * nb;
    int bid = blockIdx.x;
    int swz = (bid & 7) * (nwg >> 3) + (bid >> 3);   // XCD-contiguous (nwg % 8 == 0)
    int m0 = (swz / nb) << 7;
    int n0 = (swz % nb) << 7;
    int lane = t & 63, wid = t >> 6;
    int wm = (wid >> 1) * 64, wn = (wid & 1) * 64;
    int lr = lane & 15, lg = lane >> 4;
    f32x4 acc[4][4] = {};
    for (int k0 = 0; k0 < K; k0 += 32) {
        __syncthreads();
        #pragma unroll
        for (int it = 0; it < 2; ++it) {
            int idx = it * 256 + t;
            int row = idx >> 2, c = (idx & 3) * 8;
            gload16(&A[(size_t)(m0 + row) * K + k0 + c], &At[idx * 8]);
            gload16(&Bt[(size_t)(n0 + row) * K + k0 + c], &Bts[idx * 8]);
        }
        __syncthreads();
        half8 af[4], bf[4];
        #pragma unroll
        for (int i = 0; i < 4; ++i)
            af[i] = *(const half8*)&At[(wm + i * 16 + lr) * 32 + lg * 8];
        #pragma unroll
        for (int i = 0; i < 4; ++i)
            bf[i] = *(const half8*)&Bts[(wn + i * 16 + lr) * 32 + lg * 8];
        #pragma unroll
        for (int i = 0; i < 4; ++i)
            #pragma unroll
            for (int j = 0; j < 4; ++j)
                acc[i][j] = __builtin_amdgcn_mfma_f32_16x16x32_f16(af[i], bf[j], acc[i][j], 0, 0, 0);
    }
    #pragma unroll
    for (int i = 0; i < 4; ++i) {
        #pragma unroll
        for (int j = 0; j < 4; ++j) {
            #pragma unroll
            for (int r2 = 0; r2 < 4; ++r2) {
                int row = m0 + wm + i * 16 + lg * 4 + r2;
                int col = n0 + wn + j * 16 + lr;
                float v = acc[i][j][r2];
                if constexpr (WRITE_F32)
                    ((float*)Cout)[(size_t)row * N + col] = v + bias[col];
                else
                    ((_Float16*)Cout)[(size_t)row * N + col] = (_Float16)v;
            }
        }
    }
}

// ---------------- flash attention: diagonal pair, merged dual-group processing ----------------
// 512 blocks x 4 waves x 16 q-rows; groups A(qt=p) and B(qt=31-p) share staged K/V
// and LDS fragment reads; independent softmax chains -> ILP.
__global__ __launch_bounds__(256) void k_attn(const _Float16* __restrict__ qh,
                                              const _Float16* __restrict__ kh,
                                              const _Float16* __restrict__ vt,
                                              _Float16* __restrict__ attn_out) {
    int blk0 = blockIdx.x;                // 512
    int x = blk0 & 7;                     // XCD
    int i = blk0 >> 3;
    int bh = x * 4 + (i >> 4);            // L2-local K/V per XCD
    int p = i & 15;
    int qtA = p, qtB = 31 - p;
    int t = threadIdx.x, lane = t & 63, w = t >> 6;
    int lr = lane & 15, lg = lane >> 4;
    const _Float16* Qb = qh + (size_t)bh * S_ * HD_;
    const _Float16* Kb = kh + (size_t)bh * S_ * HD_;
    const _Float16* Vb = vt + (size_t)bh * HD_ * S_;

    __shared__ _Float16 Kt[2][64 * 64];
    __shared__ _Float16 Vt[2][64 * 64];
    __shared__ _Float16 PlB[4][16 * 64];
    __shared__ _Float16 PlA[4][16 * 64];

    const _Float16 qsc = (_Float16)0.18033688f;   // 0.125 * log2(e)
    half8 qfA[2], qfB[2];
    {
        int qA = qtA * 64 + w * 16 + lr;
        int qB = qtB * 64 + w * 16 + lr;
        #pragma unroll
        for (int dh = 0; dh < 2; ++dh) {
            qfA[dh] = *(const half8*)&Qb[(size_t)qA * 64 + dh * 32 + lg * 8];
            qfB[dh] = *(const half8*)&Qb[(size_t)qB * 64 + dh * 32 + lg * 8];
            #pragma unroll
            for (int j = 0; j < 8; ++j) { qfA[dh][j] *= qsc; qfB[dh][j] *= qsc; }
        }
    }

    f32x4 accA[4] = {}, accB[4] = {};
    float mA = -1e30f, lA = 0.f, mB = -1e30f, lB = 0.f;
    int swq = lr & 7;
    int s0 = 0, cur = 0;

    auto STAGE = [&](int bsel, int s0s) {
        #pragma unroll
        for (int cc = 0; cc < 2; ++cc) {
            int base = w * 128 + cc * 64;
            int idx = base + lane;
            int row = idx >> 3;
            int cg = (idx & 7) ^ (row & 7);
            gload16(&Kb[(size_t)(s0s + row) * 64 + cg * 8], &Kt[bsel][base * 8]);
            gload16(&Vb[(size_t)row * S_ + s0s + cg * 8], &Vt[bsel][base * 8]);
        }
    };

    // softmax (log2 domain) + pack into plw + reread A-fragments
    auto smax = [&](f32x4 (&z)[4], float& mrun, float& lrun, f32x4 (&acc)[4],
                    _Float16* plw, bool domask, int q0g, half8 (&pa)[2]) {
        int qw0 = q0g + w * 16;
        if (domask) {
            int q = qw0 + lr;
            #pragma unroll
            for (int nt = 0; nt < 4; ++nt)
                #pragma unroll
                for (int r = 0; r < 4; ++r) {
                    int kv = s0 + nt * 16 + lg * 4 + r;
                    if (kv > q) z[nt][r] = -1e30f;
                }
        }
        float mx = z[0][0];
        #pragma unroll
        for (int nt = 0; nt < 4; ++nt)
            #pragma unroll
            for (int r = 0; r < 4; ++r) mx = fmaxf(mx, z[nt][r]);
        mx = fmaxf(mx, __shfl_xor(mx, 16));
        mx = fmaxf(mx, __shfl_xor(mx, 32));

        if (!__all(mx <= mrun + 11.f)) {
            float mnew = fmaxf(mrun, mx);
            float fac = __builtin_amdgcn_exp2f(mrun - mnew);
            mrun = mnew;
            lrun *= fac;
            float facv[4];
            #pragma unroll
            for (int r = 0; r < 4; ++r) facv[r] = __shfl(fac, lg * 4 + r);
            #pragma unroll
            for (int dt = 0; dt < 4; ++dt)
                #pragma unroll
                for (int r = 0; r < 4; ++r) acc[dt][r] *= facv[r];
        }

        float rs = 0.f;
        #pragma unroll
        for (int nt = 0; nt < 4; ++nt)
            #pragma unroll
            for (int r = 0; r < 4; ++r) {
                float pv = __builtin_amdgcn_exp2f(z[nt][r] - mrun);
                z[nt][r] = pv;
                rs += pv;
            }
        rs += __shfl_xor(rs, 16);
        rs += __shfl_xor(rs, 32);
        lrun += rs;

        #pragma unroll
        for (int nt = 0; nt < 4; ++nt) {
            unsigned ua = __builtin_bit_cast(unsigned, __builtin_amdgcn_cvt_pkrtz(z[nt][0], z[nt][1]));
            unsigned ub = __builtin_bit_cast(unsigned, __builtin_amdgcn_cvt_pkrtz(z[nt][2], z[nt][3]));
            int chunk = 2 * nt + (lg >> 1);
            char* pp = (char*)plw + lr * 128 + ((chunk ^ swq) * 16) + (lg & 1) * 8;
            *(uint2*)pp = make_uint2(ua, ub);
        }
        #pragma unroll
        for (int hh = 0; hh < 2; ++hh)
            pa[hh] = *(const half8*)((const char*)plw + lr * 128 + (((4 * hh + lg) ^ swq) * 16));
    };

    STAGE(0, 0);
    for (int ti = 0; ti <= qtB; ++ti) {
        s0 = ti << 6;
        cur = ti & 1;
        __syncthreads();                  // tile ti resident
        if (ti < qtB) STAGE(cur ^ 1, s0 + 64);

        if (ti <= qtA) {
            // ---- dual: shared kf/vb loads, independent A/B chains ----
            f32x4 zB[4], zA[4];
            __builtin_amdgcn_s_setprio(1);
            #pragma unroll
            for (int nt = 0; nt < 4; ++nt) {
                int rr = nt * 16 + lr;
                half8 kf0 = *(const half8*)&Kt[cur][rr * 64 + ((lg ^ swq) * 8)];
                half8 kf1 = *(const half8*)&Kt[cur][rr * 64 + (((4 + lg) ^ swq) * 8)];
                f32x4 z = {0.f, 0.f, 0.f, 0.f};
                z = __builtin_amdgcn_mfma_f32_16x16x32_f16(kf0, qfB[0], z, 0, 0, 0);
                z = __builtin_amdgcn_mfma_f32_16x16x32_f16(kf1, qfB[1], z, 0, 0, 0);
                zB[nt] = z;
                f32x4 y = {0.f, 0.f, 0.f, 0.f};
                y = __builtin_amdgcn_mfma_f32_16x16x32_f16(kf0, qfA[0], y, 0, 0, 0);
                y = __builtin_amdgcn_mfma_f32_16x16x32_f16(kf1, qfA[1], y, 0, 0, 0);
                zA[nt] = y;
            }
            __builtin_amdgcn_s_setprio(0);
            half8 paB[2], paA[2];
            smax(zB, mB, lB, accB, &PlB[w][0], false, qtB * 64, paB);
            smax(zA, mA, lA, accA, &PlA[w][0], ti == qtA, qtA * 64, paA);
            __builtin_amdgcn_s_setprio(1);
            #pragma unroll
            for (int dt = 0; dt < 4; ++dt) {
                int vr = dt * 16 + lr;
                #pragma unroll
                for (int hh = 0; hh < 2; ++hh) {
                    half8 vb = *(const half8*)&Vt[cur][vr * 64 + (((4 * hh + lg) ^ swq) * 8)];
                    accB[dt] = __builtin_amdgcn_mfma_f32_16x16x32_f16(paB[hh], vb, accB[dt], 0, 0, 0);
                    accA[dt] = __builtin_amdgcn_mfma_f32_16x16x32_f16(paA[hh], vb, accA[dt], 0, 0, 0);
                }
            }
            __builtin_amdgcn_s_setprio(0);
        } else {
            // ---- single: B only ----
            f32x4 zB[4];
            __builtin_amdgcn_s_setprio(1);
            #pragma unroll
            for (int nt = 0; nt < 4; ++nt) {
                int rr = nt * 16 + lr;
                half8 kf0 = *(const half8*)&Kt[cur][rr * 64 + ((lg ^ swq) * 8)];
                half8 kf1 = *(const half8*)&Kt[cur][rr * 64 + (((4 + lg) ^ swq) * 8)];
                f32x4 z = {0.f, 0.f, 0.f, 0.f};
                z = __builtin_amdgcn_mfma_f32_16x16x32_f16(kf0, qfB[0], z, 0, 0, 0);
                z = __builtin_amdgcn_mfma_f32_16x16x32_f16(kf1, qfB[1], z, 0, 0, 0);
                zB[nt] = z;
            }
            __builtin_amdgcn_s_setprio(0);
            half8 paB[2];
            smax(zB, mB, lB, accB, &PlB[w][0], ti == qtB, qtB * 64, paB);
            __builtin_amdgcn_s_setprio(1);
            #pragma unroll
            for (int dt = 0; dt < 4; ++dt) {
                int vr = dt * 16 + lr;
                #pragma unroll
                for (int hh = 0; hh < 2; ++hh) {
                    half8 vb = *(const half8*)&Vt[cur][vr * 64 + (((4 * hh + lg) ^ swq) * 8)];
                    accB[dt] = __builtin_amdgcn_mfma_f32_16x16x32_f16(paB[hh], vb, accB[dt], 0, 0, 0);
                }
            }
            __builtin_amdgcn_s_setprio(0);
        }
    }

    int b = bh >> 4, h = bh & 15;
    auto writeout = [&](const f32x4* acc, float lrun, int q0g) {
        float linv[4];
        #pragma unroll
        for (int r = 0; r < 4; ++r) linv[r] = 1.0f / __shfl(lrun, lg * 4 + r);
        #pragma unroll
        for (int dt = 0; dt < 4; ++dt)
            #pragma unroll
            for (int r = 0; r < 4; ++r) {
                int s = q0g + w * 16 + lg * 4 + r;
                attn_out[((size_t)b * S_ + s) * HID_ + h * 64 + dt * 16 + lr] =
                    (_Float16)(acc[dt][r] * linv[r]);
            }
    };
    writeout(accB, lB, qtB * 64);
    writeout(accA, lA, qtA * 64);
}

// ---------------- launch ----------------

extern "C" void kernel_launch(void* const* d_in, const int* in_sizes, int n_in,
                              void* d_out, int out_size, void* d_ws, size_t ws_size,
                              hipStream_t stream) {
    const float* hidden  = (const float*)d_in[0];
    const float* w_qkv   = (const float*)d_in[1];
    const float* w_dense = (const float*)d_in[2];
    const float* b_dense = (const float*)d_in[3];
    float* out = (float*)d_out;
    char* ws = (char*)d_ws;

    _Float16* hh     = (_Float16*)(ws + 0);          // 8 MB; reused as qh
    _Float16* wqkvT  = (_Float16*)(ws + 8388608);    // 6 MB
    _Float16* wdT    = (_Float16*)(ws + 14680064);   // 2 MB
    float*    cos_t  = (float*)   (ws + 16777216);   // 256 KB
    float*    sin_t  = (float*)   (ws + 17039360);   // 256 KB
    _Float16* fused  = (_Float16*)(ws + 17301504);   // 24 MB; reused as attn_out
    _Float16* kh     = (_Float16*)(ws + 42467328);   // 8 MB
    _Float16* vt     = (_Float16*)(ws + 50855936);   // 8 MB
    _Float16* qh     = hh;
    _Float16* attn_o = fused;

    k_prep<<<6400, 256, 0, stream>>>(hidden, w_qkv, w_dense, hh, wqkvT, wdT, cos_t, sin_t);

    k_gemm<false><<<(B_ * S_ / 128) * (3 * HID_ / 128), 256, 0, stream>>>(
        hh, wqkvT, (void*)fused, nullptr, B_ * S_, 3 * HID_, HID_);

    k_reshape_rope<<<B_ * NH_ * (S_ / 64), 256, 0, stream>>>(fused, cos_t, sin_t, qh, kh, vt);

    k_attn<<<B_ * NH_ * (S_ / 64) / 2, 256, 0, stream>>>(qh, kh, vt, attn_o);

    k_gemm<true><<<(B_ * S_ / 128) * (HID_ / 128), 256, 0, stream>>>(
        attn_o, wdT, (void*)out, b_dense, B_ * S_, HID_, HID_);
}

// Round 9
// 200.181 us; speedup vs baseline: 1.7193x; 1.0241x over previous
//
#include <hip/hip_runtime.h>

#define B_ 2
#define S_ 2048
#define HID_ 1024
#define NH_ 16
#define HD_ 64

typedef _Float16 half8 __attribute__((ext_vector_type(8)));
typedef float f32x4 __attribute__((ext_vector_type(4)));

__device__ __forceinline__ void gload16(const _Float16* g, _Float16* l) {
    __builtin_amdgcn_global_load_lds(
        (const __attribute__((address_space(1))) void*)g,
        (__attribute__((address_space(3))) void*)l, 16, 0, 0);
}

// ---------------- fused prep: cast + both weight transposes + rope tables ----------------

__device__ __forceinline__ void tr32(const float* __restrict__ in, _Float16* __restrict__ out,
                                     int K, int N, int n0, int k0, int tx, int ty,
                                     float (*tile)[33]) {
    #pragma unroll
    for (int i2 = 0; i2 < 32; i2 += 8)
        tile[ty + i2][tx] = in[(size_t)(k0 + ty + i2) * N + n0 + tx];
    __syncthreads();
    #pragma unroll
    for (int i2 = 0; i2 < 32; i2 += 8)
        out[(size_t)(n0 + ty + i2) * K + k0 + tx] = (_Float16)tile[tx][ty + i2];
}

__global__ __launch_bounds__(256) void k_prep(
        const float* __restrict__ hidden, const float* __restrict__ w_qkv,
        const float* __restrict__ w_dense, _Float16* __restrict__ hh,
        _Float16* __restrict__ wqkvT, _Float16* __restrict__ wdT,
        float* __restrict__ cos_t, float* __restrict__ sin_t) {
    int b = blockIdx.x, t = threadIdx.x;
    __shared__ float tile[32][33];
    if (b < 2048) {                        // cast hidden f32 -> f16 (8/thread)
        int i = (b * 256 + t) * 8;
        float4 a = *(const float4*)&hidden[i];
        float4 c = *(const float4*)&hidden[i + 4];
        half8 h;
        h[0] = (_Float16)a.x; h[1] = (_Float16)a.y; h[2] = (_Float16)a.z; h[3] = (_Float16)a.w;
        h[4] = (_Float16)c.x; h[5] = (_Float16)c.y; h[6] = (_Float16)c.z; h[7] = (_Float16)c.w;
        *(half8*)&hh[i] = h;
    } else if (b < 5120) {                 // w_qkv^T: 96 x 32 tiles
        int bb = b - 2048;
        tr32(w_qkv, wqkvT, HID_, 3 * HID_, (bb % 96) * 32, (bb / 96) * 32, t & 31, t >> 5, tile);
    } else if (b < 6144) {                 // w_dense^T: 32 x 32 tiles
        int bb = b - 5120;
        tr32(w_dense, wdT, HID_, HID_, (bb % 32) * 32, (bb / 32) * 32, t & 31, t >> 5, tile);
    } else {                               // rope tables: 8 rows/block
        int bb = b - 6144;
        int s = bb * 8 + (t >> 5);
        int ii = t & 31;
        float inv = powf(10000.0f, -(float)(2 * ii) / 64.0f);
        float ang = (float)s * inv;
        cos_t[s * 32 + ii] = cosf(ang);
        sin_t[s * 32 + ii] = sinf(ang);
    }
}

// fused [B*S][3072] f16 -> qh,kh [b,h,s,d] with RoPE; vt [b,h,d,s]
__global__ __launch_bounds__(256) void k_reshape_rope(
        const _Float16* __restrict__ fused, const float* __restrict__ cos_t,
        const float* __restrict__ sin_t, _Float16* __restrict__ qh,
        _Float16* __restrict__ kh, _Float16* __restrict__ vt) {
    int blk = blockIdx.x;                 // 1024
    int s0 = (blk & 31) * 64;
    int bh = blk >> 5;
    int h = bh & 15;
    int t = threadIdx.x;
    int r = t >> 2, dq0 = (t & 3) * 16;
    int s = s0 + r;
    const _Float16* fr = fused + ((size_t)(bh >> 4) * S_ + s) * 3072;
    size_t qkbase = ((size_t)bh * S_ + s) * HD_;
    int pq0 = dq0 ^ 32;
    float sgn = (dq0 < 32) ? -1.f : 1.f;

    half8 qm[2], qp[2], km[2], kp[2], vm[2];
    qm[0] = *(const half8*)&fr[h * 64 + dq0];
    qm[1] = *(const half8*)&fr[h * 64 + dq0 + 8];
    qp[0] = *(const half8*)&fr[h * 64 + pq0];
    qp[1] = *(const half8*)&fr[h * 64 + pq0 + 8];
    km[0] = *(const half8*)&fr[1024 + h * 64 + dq0];
    km[1] = *(const half8*)&fr[1024 + h * 64 + dq0 + 8];
    kp[0] = *(const half8*)&fr[1024 + h * 64 + pq0];
    kp[1] = *(const half8*)&fr[1024 + h * 64 + pq0 + 8];
    vm[0] = *(const half8*)&fr[2048 + h * 64 + dq0];
    vm[1] = *(const half8*)&fr[2048 + h * 64 + dq0 + 8];

    const float* cb = &cos_t[s * 32 + (dq0 & 31)];
    const float* sb = &sin_t[s * 32 + (dq0 & 31)];
    half8 qo[2], ko[2];
    #pragma unroll
    for (int v8 = 0; v8 < 2; ++v8)
        #pragma unroll
        for (int j = 0; j < 8; ++j) {
            float cs = cb[v8 * 8 + j], sn = sb[v8 * 8 + j];
            qo[v8][j] = (_Float16)((float)qm[v8][j] * cs + sgn * (float)qp[v8][j] * sn);
            ko[v8][j] = (_Float16)((float)km[v8][j] * cs + sgn * (float)kp[v8][j] * sn);
        }
    *(half8*)&qh[qkbase + dq0]     = qo[0];
    *(half8*)&qh[qkbase + dq0 + 8] = qo[1];
    *(half8*)&kh[qkbase + dq0]     = ko[0];
    *(half8*)&kh[qkbase + dq0 + 8] = ko[1];

    __shared__ _Float16 vtile[64][80];
    *(half8*)&vtile[r][dq0]     = vm[0];
    *(half8*)&vtile[r][dq0 + 8] = vm[1];
    __syncthreads();
    int dd = t >> 2, sc0 = (t & 3) * 16;
    _Float16 vv[16];
    #pragma unroll
    for (int j = 0; j < 16; ++j)
        vv[j] = vtile[sc0 + j][dd];
    size_t vbase = ((size_t)bh * HD_ + dd) * (size_t)S_ + s0 + sc0;
    *(half8*)&vt[vbase]     = *(half8*)&vv[0];
    *(half8*)&vt[vbase + 8] = *(half8*)&vv[8];
}

// ---------------- GEMM (C = A * Bt^T), dbuf LDS + async prefetch (m97 schedule) ----------------
template <bool WRITE_F32>
__global__ __launch_bounds__(256) void k_gemm(const _Float16* __restrict__ A,
                                              const _Float16* __restrict__ Bt,
                                              void* __restrict__ Cout,
                                              const float* __restrict__ bias,
                                              int M, int N, int K) {
    __shared__ _Float16 At[2][128 * 32];
    __shared__ _Float16 Bts[2][128 * 32];
    int t = threadIdx.x;
    int nb = N >> 7;
    int nwg = (M >> 7) * nb;
    int bid = blockIdx.x;
    int swz = (bid & 7) * (nwg >> 3) + (bid >> 3);   // XCD-contiguous (nwg % 8 == 0)
    int m0 = (swz / nb) << 7;
    int n0 = (swz % nb) << 7;
    int lane = t & 63, wid = t >> 6;
    int wm = (wid >> 1) * 64, wn = (wid & 1) * 64;
    int lr = lane & 15, lg = lane >> 4;

    int srow = t >> 2, sc = (t & 3) * 8;            // staging coords (2 rows per thread)
    const _Float16* Ap  = &A[(size_t)(m0 + srow) * K + sc];
    const _Float16* Ap2 = &A[(size_t)(m0 + 64 + srow) * K + sc];
    const _Float16* Bp  = &Bt[(size_t)(n0 + srow) * K + sc];
    const _Float16* Bp2 = &Bt[(size_t)(n0 + 64 + srow) * K + sc];

    auto STAGE = [&](int bsel, int k0) {
        gload16(Ap + k0,  &At[bsel][t * 8]);
        gload16(Ap2 + k0, &At[bsel][(256 + t) * 8]);
        gload16(Bp + k0,  &Bts[bsel][t * 8]);
        gload16(Bp2 + k0, &Bts[bsel][(256 + t) * 8]);
    };

    f32x4 acc[4][4] = {};
    STAGE(0, 0);
    int nk = K >> 5;
    for (int ti = 0; ti < nk; ++ti) {
        int cur = ti & 1;
        __syncthreads();                             // tile ti resident (drains vmcnt)
        if (ti + 1 < nk) STAGE(cur ^ 1, (ti + 1) << 5);   // prefetch hides under compute
        half8 af[4], bf[4];
        #pragma unroll
        for (int i = 0; i < 4; ++i)
            af[i] = *(const half8*)&At[cur][(wm + i * 16 + lr) * 32 + lg * 8];
        #pragma unroll
        for (int i = 0; i < 4; ++i)
            bf[i] = *(const half8*)&Bts[cur][(wn + i * 16 + lr) * 32 + lg * 8];
        __builtin_amdgcn_s_setprio(1);
        #pragma unroll
        for (int i = 0; i < 4; ++i)
            #pragma unroll
            for (int j = 0; j < 4; ++j)
                acc[i][j] = __builtin_amdgcn_mfma_f32_16x16x32_f16(af[i], bf[j], acc[i][j], 0, 0, 0);
        __builtin_amdgcn_s_setprio(0);
        __syncthreads();                             // all reads of buf[cur] done before rewrite
    }
    #pragma unroll
    for (int i = 0; i < 4; ++i) {
        #pragma unroll
        for (int j = 0; j < 4; ++j) {
            #pragma unroll
            for (int r2 = 0; r2 < 4; ++r2) {
                int row = m0 + wm + i * 16 + lg * 4 + r2;
                int col = n0 + wn + j * 16 + lr;
                float v = acc[i][j][r2];
                if constexpr (WRITE_F32)
                    ((float*)Cout)[(size_t)row * N + col] = v + bias[col];
                else
                    ((_Float16*)Cout)[(size_t)row * N + col] = (_Float16)v;
            }
        }
    }
}

// ---------------- flash attention: diagonal pair, merged dual-group processing ----------------
__global__ __launch_bounds__(256) void k_attn(const _Float16* __restrict__ qh,
                                              const _Float16* __restrict__ kh,
                                              const _Float16* __restrict__ vt,
                                              _Float16* __restrict__ attn_out) {
    int blk0 = blockIdx.x;                // 512
    int x = blk0 & 7;                     // XCD
    int i = blk0 >> 3;
    int bh = x * 4 + (i >> 4);            // L2-local K/V per XCD
    int p = i & 15;
    int qtA = p, qtB = 31 - p;
    int t = threadIdx.x, lane = t & 63, w = t >> 6;
    int lr = lane & 15, lg = lane >> 4;
    const _Float16* Qb = qh + (size_t)bh * S_ * HD_;
    const _Float16* Kb = kh + (size_t)bh * S_ * HD_;
    const _Float16* Vb = vt + (size_t)bh * HD_ * S_;

    __shared__ _Float16 Kt[2][64 * 64];
    __shared__ _Float16 Vt[2][64 * 64];
    __shared__ _Float16 PlB[4][16 * 64];
    __shared__ _Float16 PlA[4][16 * 64];

    const _Float16 qsc = (_Float16)0.18033688f;   // 0.125 * log2(e)
    half8 qfA[2], qfB[2];
    {
        int qA = qtA * 64 + w * 16 + lr;
        int qB = qtB * 64 + w * 16 + lr;
        #pragma unroll
        for (int dh = 0; dh < 2; ++dh) {
            qfA[dh] = *(const half8*)&Qb[(size_t)qA * 64 + dh * 32 + lg * 8];
            qfB[dh] = *(const half8*)&Qb[(size_t)qB * 64 + dh * 32 + lg * 8];
            #pragma unroll
            for (int j = 0; j < 8; ++j) { qfA[dh][j] *= qsc; qfB[dh][j] *= qsc; }
        }
    }

    f32x4 accA[4] = {}, accB[4] = {};
    float mA = -1e30f, lA = 0.f, mB = -1e30f, lB = 0.f;
    int swq = lr & 7;
    int s0 = 0, cur = 0;

    auto STAGE = [&](int bsel, int s0s) {
        #pragma unroll
        for (int cc = 0; cc < 2; ++cc) {
            int base = w * 128 + cc * 64;
            int idx = base + lane;
            int row = idx >> 3;
            int cg = (idx & 7) ^ (row & 7);
            gload16(&Kb[(size_t)(s0s + row) * 64 + cg * 8], &Kt[bsel][base * 8]);
            gload16(&Vb[(size_t)row * S_ + s0s + cg * 8], &Vt[bsel][base * 8]);
        }
    };

    auto smax = [&](f32x4 (&z)[4], float& mrun, float& lrun, f32x4 (&acc)[4],
                    _Float16* plw, bool domask, int q0g, half8 (&pa)[2]) {
        int qw0 = q0g + w * 16;
        if (domask) {
            int q = qw0 + lr;
            #pragma unroll
            for (int nt = 0; nt < 4; ++nt)
                #pragma unroll
                for (int r = 0; r < 4; ++r) {
                    int kv = s0 + nt * 16 + lg * 4 + r;
                    if (kv > q) z[nt][r] = -1e30f;
                }
        }
        float mx = z[0][0];
        #pragma unroll
        for (int nt = 0; nt < 4; ++nt)
            #pragma unroll
            for (int r = 0; r < 4; ++r) mx = fmaxf(mx, z[nt][r]);
        mx = fmaxf(mx, __shfl_xor(mx, 16));
        mx = fmaxf(mx, __shfl_xor(mx, 32));

        if (!__all(mx <= mrun + 11.f)) {
            float mnew = fmaxf(mrun, mx);
            float fac = __builtin_amdgcn_exp2f(mrun - mnew);
            mrun = mnew;
            lrun *= fac;
            float facv[4];
            #pragma unroll
            for (int r = 0; r < 4; ++r) facv[r] = __shfl(fac, lg * 4 + r);
            #pragma unroll
            for (int dt = 0; dt < 4; ++dt)
                #pragma unroll
                for (int r = 0; r < 4; ++r) acc[dt][r] *= facv[r];
        }

        float rs = 0.f;
        #pragma unroll
        for (int nt = 0; nt < 4; ++nt)
            #pragma unroll
            for (int r = 0; r < 4; ++r) {
                float pv = __builtin_amdgcn_exp2f(z[nt][r] - mrun);
                z[nt][r] = pv;
                rs += pv;
            }
        rs += __shfl_xor(rs, 16);
        rs += __shfl_xor(rs, 32);
        lrun += rs;

        #pragma unroll
        for (int nt = 0; nt < 4; ++nt) {
            unsigned ua = __builtin_bit_cast(unsigned, __builtin_amdgcn_cvt_pkrtz(z[nt][0], z[nt][1]));
            unsigned ub = __builtin_bit_cast(unsigned, __builtin_amdgcn_cvt_pkrtz(z[nt][2], z[nt][3]));
            int chunk = 2 * nt + (lg >> 1);
            char* pp = (char*)plw + lr * 128 + ((chunk ^ swq) * 16) + (lg & 1) * 8;
            *(uint2*)pp = make_uint2(ua, ub);
        }
        #pragma unroll
        for (int hh = 0; hh < 2; ++hh)
            pa[hh] = *(const half8*)((const char*)plw + lr * 128 + (((4 * hh + lg) ^ swq) * 16));
    };

    STAGE(0, 0);
    for (int ti = 0; ti <= qtB; ++ti) {
        s0 = ti << 6;
        cur = ti & 1;
        __syncthreads();                  // tile ti resident
        if (ti < qtB) STAGE(cur ^ 1, s0 + 64);

        if (ti <= qtA) {
            f32x4 zB[4], zA[4];
            __builtin_amdgcn_s_setprio(1);
            #pragma unroll
            for (int nt = 0; nt < 4; ++nt) {
                int rr = nt * 16 + lr;
                half8 kf0 = *(const half8*)&Kt[cur][rr * 64 + ((lg ^ swq) * 8)];
                half8 kf1 = *(const half8*)&Kt[cur][rr * 64 + (((4 + lg) ^ swq) * 8)];
                f32x4 z = {0.f, 0.f, 0.f, 0.f};
                z = __builtin_amdgcn_mfma_f32_16x16x32_f16(kf0, qfB[0], z, 0, 0, 0);
                z = __builtin_amdgcn_mfma_f32_16x16x32_f16(kf1, qfB[1], z, 0, 0, 0);
                zB[nt] = z;
                f32x4 y = {0.f, 0.f, 0.f, 0.f};
                y = __builtin_amdgcn_mfma_f32_16x16x32_f16(kf0, qfA[0], y, 0, 0, 0);
                y = __builtin_amdgcn_mfma_f32_16x16x32_f16(kf1, qfA[1], y, 0, 0, 0);
                zA[nt] = y;
            }
            __builtin_amdgcn_s_setprio(0);
            half8 paB[2], paA[2];
            smax(zB, mB, lB, accB, &PlB[w][0], false, qtB * 64, paB);
            smax(zA, mA, lA, accA, &PlA[w][0], ti == qtA, qtA * 64, paA);
            __builtin_amdgcn_s_setprio(1);
            #pragma unroll
            for (int dt = 0; dt < 4; ++dt) {
                int vr = dt * 16 + lr;
                #pragma unroll
                for (int hh = 0; hh < 2; ++hh) {
                    half8 vb = *(const half8*)&Vt[cur][vr * 64 + (((4 * hh + lg) ^ swq) * 8)];
                    accB[dt] = __builtin_amdgcn_mfma_f32_16x16x32_f16(paB[hh], vb, accB[dt], 0, 0, 0);
                    accA[dt] = __builtin_amdgcn_mfma_f32_16x16x32_f16(paA[hh], vb, accA[dt], 0, 0, 0);
                }
            }
            __builtin_amdgcn_s_setprio(0);
        } else {
            f32x4 zB[4];
            __builtin_amdgcn_s_setprio(1);
            #pragma unroll
            for (int nt = 0; nt < 4; ++nt) {
                int rr = nt * 16 + lr;
                half8 kf0 = *(const half8*)&Kt[cur][rr * 64 + ((lg ^ swq) * 8)];
                half8 kf1 = *(const half8*)&Kt[cur][rr * 64 + (((4 + lg) ^ swq) * 8)];
                f32x4 z = {0.f, 0.f, 0.f, 0.f};
                z = __builtin_amdgcn_mfma_f32_16x16x32_f16(kf0, qfB[0], z, 0, 0, 0);
                z = __builtin_amdgcn_mfma_f32_16x16x32_f16(kf1, qfB[1], z, 0, 0, 0);
                zB[nt] = z;
            }
            __builtin_amdgcn_s_setprio(0);
            half8 paB[2];
            smax(zB, mB, lB, accB, &PlB[w][0], ti == qtB, qtB * 64, paB);
            __builtin_amdgcn_s_setprio(1);
            #pragma unroll
            for (int dt = 0; dt < 4; ++dt) {
                int vr = dt * 16 + lr;
                #pragma unroll
                for (int hh = 0; hh < 2; ++hh) {
                    half8 vb = *(const half8*)&Vt[cur][vr * 64 + (((4 * hh + lg) ^ swq) * 8)];
                    accB[dt] = __builtin_amdgcn_mfma_f32_16x16x32_f16(paB[hh], vb, accB[dt], 0, 0, 0);
                }
            }
            __builtin_amdgcn_s_setprio(0);
        }
    }

    int b = bh >> 4, h = bh & 15;
    auto writeout = [&](const f32x4* acc, float lrun, int q0g) {
        float linv[4];
        #pragma unroll
        for (int r = 0; r < 4; ++r) linv[r] = 1.0f / __shfl(lrun, lg * 4 + r);
        #pragma unroll
        for (int dt = 0; dt < 4; ++dt)
            #pragma unroll
            for (int r = 0; r < 4; ++r) {
                int s = q0g + w * 16 + lg * 4 + r;
                attn_out[((size_t)b * S_ + s) * HID_ + h * 64 + dt * 16 + lr] =
                    (_Float16)(acc[dt][r] * linv[r]);
            }
    };
    writeout(accB, lB, qtB * 64);
    writeout(accA, lA, qtA * 64);
}

// ---------------- launch ----------------

extern "C" void kernel_launch(void* const* d_in, const int* in_sizes, int n_in,
                              void* d_out, int out_size, void* d_ws, size_t ws_size,
                              hipStream_t stream) {
    const float* hidden  = (const float*)d_in[0];
    const float* w_qkv   = (const float*)d_in[1];
    const float* w_dense = (const float*)d_in[2];
    const float* b_dense = (const float*)d_in[3];
    float* out = (float*)d_out;
    char* ws = (char*)d_ws;

    _Float16* hh     = (_Float16*)(ws + 0);          // 8 MB; reused as qh
    _Float16* wqkvT  = (_Float16*)(ws + 8388608);    // 6 MB
    _Float16* wdT    = (_Float16*)(ws + 14680064);   // 2 MB
    float*    cos_t  = (float*)   (ws + 16777216);   // 256 KB
    float*    sin_t  = (float*)   (ws + 17039360);   // 256 KB
    _Float16* fused  = (_Float16*)(ws + 17301504);   // 24 MB; reused as attn_out
    _Float16* kh     = (_Float16*)(ws + 42467328);   // 8 MB
    _Float16* vt     = (_Float16*)(ws + 50855936);   // 8 MB
    _Float16* qh     = hh;
    _Float16* attn_o = fused;

    k_prep<<<6400, 256, 0, stream>>>(hidden, w_qkv, w_dense, hh, wqkvT, wdT, cos_t, sin_t);

    k_gemm<false><<<(B_ * S_ / 128) * (3 * HID_ / 128), 256, 0, stream>>>(
        hh, wqkvT, (void*)fused, nullptr, B_ * S_, 3 * HID_, HID_);

    k_reshape_rope<<<B_ * NH_ * (S_ / 64), 256, 0, stream>>>(fused, cos_t, sin_t, qh, kh, vt);

    k_attn<<<B_ * NH_ * (S_ / 64) / 2, 256, 0, stream>>>(qh, kh, vt, attn_o);

    k_gemm<true><<<(B_ * S_ / 128) * (HID_ / 128), 256, 0, stream>>>(
        attn_o, wdT, (void*)out, b_dense, B_ * S_, HID_, HID_);
}

// Round 10
// 194.313 us; speedup vs baseline: 1.7712x; 1.0302x over previous
//
#include <hip/hip_runtime.h>

#define B_ 2
#define S_ 2048
#define HID_ 1024
#define NH_ 16
#define HD_ 64

typedef _Float16 half8 __attribute__((ext_vector_type(8)));
typedef float f32x4 __attribute__((ext_vector_type(4)));

__device__ __forceinline__ void gload16(const _Float16* g, _Float16* l) {
    __builtin_amdgcn_global_load_lds(
        (const __attribute__((address_space(1))) void*)g,
        (__attribute__((address_space(3))) void*)l, 16, 0, 0);
}

// ---------------- fused prep: cast + both weight transposes + rope tables ----------------

__device__ __forceinline__ void tr32(const float* __restrict__ in, _Float16* __restrict__ out,
                                     int K, int N, int n0, int k0, int tx, int ty,
                                     float (*tile)[33]) {
    #pragma unroll
    for (int i2 = 0; i2 < 32; i2 += 8)
        tile[ty + i2][tx] = in[(size_t)(k0 + ty + i2) * N + n0 + tx];
    __syncthreads();
    #pragma unroll
    for (int i2 = 0; i2 < 32; i2 += 8)
        out[(size_t)(n0 + ty + i2) * K + k0 + tx] = (_Float16)tile[tx][ty + i2];
}

__global__ __launch_bounds__(256) void k_prep(
        const float* __restrict__ hidden, const float* __restrict__ w_qkv,
        const float* __restrict__ w_dense, _Float16* __restrict__ hh,
        _Float16* __restrict__ wqkvT, _Float16* __restrict__ wdT,
        float* __restrict__ cos_t, float* __restrict__ sin_t) {
    int b = blockIdx.x, t = threadIdx.x;
    __shared__ float tile[32][33];
    if (b < 2048) {                        // cast hidden f32 -> f16 (8/thread)
        int i = (b * 256 + t) * 8;
        float4 a = *(const float4*)&hidden[i];
        float4 c = *(const float4*)&hidden[i + 4];
        half8 h;
        h[0] = (_Float16)a.x; h[1] = (_Float16)a.y; h[2] = (_Float16)a.z; h[3] = (_Float16)a.w;
        h[4] = (_Float16)c.x; h[5] = (_Float16)c.y; h[6] = (_Float16)c.z; h[7] = (_Float16)c.w;
        *(half8*)&hh[i] = h;
    } else if (b < 5120) {                 // w_qkv^T: 96 x 32 tiles
        int bb = b - 2048;
        tr32(w_qkv, wqkvT, HID_, 3 * HID_, (bb % 96) * 32, (bb / 96) * 32, t & 31, t >> 5, tile);
    } else if (b < 6144) {                 // w_dense^T: 32 x 32 tiles
        int bb = b - 5120;
        tr32(w_dense, wdT, HID_, HID_, (bb % 32) * 32, (bb / 32) * 32, t & 31, t >> 5, tile);
    } else {                               // rope tables: 8 rows/block
        int bb = b - 6144;
        int s = bb * 8 + (t >> 5);
        int ii = t & 31;
        float inv = powf(10000.0f, -(float)(2 * ii) / 64.0f);
        float ang = (float)s * inv;
        cos_t[s * 32 + ii] = cosf(ang);
        sin_t[s * 32 + ii] = sinf(ang);
    }
}

// ---------------- GEMM (C = A * Bt^T), dbuf LDS + async prefetch ----------------
// QKV_EP: epilogue applies RoPE in-register (partner d^32 = acc[i][j^2][r]) and writes
// qh/kh [bh][s][d] + vt [bh][d][s] (via LDS transpose) directly -> no fused buffer.
template <bool WRITE_F32, bool QKV_EP>
__global__ __launch_bounds__(256) void k_gemm(const _Float16* __restrict__ A,
                                              const _Float16* __restrict__ Bt,
                                              void* __restrict__ Cout,
                                              const float* __restrict__ bias,
                                              int M, int N, int K,
                                              const float* __restrict__ cos_t,
                                              const float* __restrict__ sin_t,
                                              _Float16* __restrict__ qh,
                                              _Float16* __restrict__ kh,
                                              _Float16* __restrict__ vt) {
    __shared__ _Float16 smem[16640];                 // At|Bts (2x 8192) or V-transpose [128][130]
    _Float16* At  = smem;                            // [2][128*32]
    _Float16* Bts = smem + 8192;
    int t = threadIdx.x;
    int nb = N >> 7;
    int nwg = (M >> 7) * nb;
    int bid = blockIdx.x;
    int swz = (bid & 7) * (nwg >> 3) + (bid >> 3);   // XCD-contiguous (nwg % 8 == 0)
    int m0 = (swz / nb) << 7;
    int n0 = (swz % nb) << 7;
    int lane = t & 63, wid = t >> 6;
    int wm = (wid >> 1) * 64, wn = (wid & 1) * 64;
    int lr = lane & 15, lg = lane >> 4;

    int srow = t >> 2, sc = (t & 3) * 8;            // staging coords
    const _Float16* Ap  = &A[(size_t)(m0 + srow) * K + sc];
    const _Float16* Ap2 = &A[(size_t)(m0 + 64 + srow) * K + sc];
    const _Float16* Bp  = &Bt[(size_t)(n0 + srow) * K + sc];
    const _Float16* Bp2 = &Bt[(size_t)(n0 + 64 + srow) * K + sc];

    auto STAGE = [&](int bsel, int k0) {
        gload16(Ap + k0,  &At[bsel * 4096 + t * 8]);
        gload16(Ap2 + k0, &At[bsel * 4096 + (256 + t) * 8]);
        gload16(Bp + k0,  &Bts[bsel * 4096 + t * 8]);
        gload16(Bp2 + k0, &Bts[bsel * 4096 + (256 + t) * 8]);
    };

    f32x4 acc[4][4] = {};
    STAGE(0, 0);
    int nk = K >> 5;
    for (int ti = 0; ti < nk; ++ti) {
        int cur = ti & 1;
        __syncthreads();                             // tile ti resident (drains vmcnt)
        if (ti + 1 < nk) STAGE(cur ^ 1, (ti + 1) << 5);
        half8 af[4], bf[4];
        #pragma unroll
        for (int i = 0; i < 4; ++i)
            af[i] = *(const half8*)&At[cur * 4096 + (wm + i * 16 + lr) * 32 + lg * 8];
        #pragma unroll
        for (int i = 0; i < 4; ++i)
            bf[i] = *(const half8*)&Bts[cur * 4096 + (wn + i * 16 + lr) * 32 + lg * 8];
        __builtin_amdgcn_s_setprio(1);
        #pragma unroll
        for (int i = 0; i < 4; ++i)
            #pragma unroll
            for (int j = 0; j < 4; ++j)
                acc[i][j] = __builtin_amdgcn_mfma_f32_16x16x32_f16(af[i], bf[j], acc[i][j], 0, 0, 0);
        __builtin_amdgcn_s_setprio(0);
        __syncthreads();
    }

    if constexpr (QKV_EP) {
        int sect = n0 >> 10;                         // 0=Q 1=K 2=V (tile never straddles)
        int h0 = (n0 & 1023) >> 6;
        int h = h0 + (wn >> 6);                      // wave-uniform head
        if (sect < 2) {
            _Float16* dst = (sect == 0) ? qh : kh;
            #pragma unroll
            for (int i = 0; i < 4; ++i) {
                int rowb = m0 + wm + i * 16 + lg * 4;
                #pragma unroll
                for (int r = 0; r < 4; ++r) {
                    int row = rowb + r;
                    int s = row & (S_ - 1);
                    int b2 = row >> 11;
                    float cs0 = cos_t[s * 32 + lr];
                    float sn0 = sin_t[s * 32 + lr];
                    float cs1 = cos_t[s * 32 + 16 + lr];
                    float sn1 = sin_t[s * 32 + 16 + lr];
                    size_t base = (((size_t)b2 * NH_ + h) * S_ + s) * HD_;
                    #pragma unroll
                    for (int j = 0; j < 4; ++j) {
                        int d = j * 16 + lr;
                        float v = acc[i][j][r];
                        float pv = acc[i][j ^ 2][r];
                        float cs = (j & 1) ? cs1 : cs0;
                        float sn = (j & 1) ? sn1 : sn0;
                        float res = v * cs + ((j < 2) ? -pv : pv) * sn;
                        dst[base + d] = (_Float16)res;
                    }
                }
            }
        } else {
            // V: transpose s<->d through LDS (pad 130 -> <=2-way write, 4-way read)
            _Float16 (*vts)[130] = (_Float16(*)[130])smem;
            #pragma unroll
            for (int i = 0; i < 4; ++i)
                #pragma unroll
                for (int j = 0; j < 4; ++j)
                    #pragma unroll
                    for (int r = 0; r < 4; ++r)
                        vts[wm + i * 16 + lg * 4 + r][wn + j * 16 + lr] = (_Float16)acc[i][j][r];
            __syncthreads();
            int b2 = m0 >> 11;
            int sbase = m0 & (S_ - 1);
            int dd = t >> 2, sc0 = (t & 3) * 16;     // reshape-proven pattern per 64x64 subtile
            #pragma unroll
            for (int hs = 0; hs < 2; ++hs)
                #pragma unroll
                for (int dh = 0; dh < 2; ++dh) {
                    _Float16 tmp[16];
                    #pragma unroll
                    for (int jj = 0; jj < 16; ++jj)
                        tmp[jj] = vts[hs * 64 + sc0 + jj][dh * 64 + dd];
                    size_t vrow = (((size_t)b2 * NH_ + h0 + dh) * HD_ + dd) * S_
                                  + sbase + hs * 64 + sc0;
                    *(half8*)&vt[vrow]     = *(half8*)&tmp[0];
                    *(half8*)&vt[vrow + 8] = *(half8*)&tmp[8];
                }
        }
    } else {
        #pragma unroll
        for (int i = 0; i < 4; ++i)
            #pragma unroll
            for (int j = 0; j < 4; ++j)
                #pragma unroll
                for (int r2 = 0; r2 < 4; ++r2) {
                    int row = m0 + wm + i * 16 + lg * 4 + r2;
                    int col = n0 + wn + j * 16 + lr;
                    float v = acc[i][j][r2];
                    if constexpr (WRITE_F32)
                        ((float*)Cout)[(size_t)row * N + col] = v + bias[col];
                    else
                        ((_Float16*)Cout)[(size_t)row * N + col] = (_Float16)v;
                }
    }
}

// ---------------- flash attention: diagonal pair, merged dual-group processing ----------------
__global__ __launch_bounds__(256) void k_attn(const _Float16* __restrict__ qh,
                                              const _Float16* __restrict__ kh,
                                              const _Float16* __restrict__ vt,
                                              _Float16* __restrict__ attn_out) {
    int blk0 = blockIdx.x;                // 512
    int x = blk0 & 7;                     // XCD
    int i = blk0 >> 3;
    int bh = x * 4 + (i >> 4);            // L2-local K/V per XCD
    int p = i & 15;
    int qtA = p, qtB = 31 - p;
    int t = threadIdx.x, lane = t & 63, w = t >> 6;
    int lr = lane & 15, lg = lane >> 4;
    const _Float16* Qb = qh + (size_t)bh * S_ * HD_;
    const _Float16* Kb = kh + (size_t)bh * S_ * HD_;
    const _Float16* Vb = vt + (size_t)bh * HD_ * S_;

    __shared__ _Float16 Kt[2][64 * 64];
    __shared__ _Float16 Vt[2][64 * 64];
    __shared__ _Float16 PlB[4][16 * 64];
    __shared__ _Float16 PlA[4][16 * 64];

    const _Float16 qsc = (_Float16)0.18033688f;   // 0.125 * log2(e)
    half8 qfA[2], qfB[2];
    {
        int qA = qtA * 64 + w * 16 + lr;
        int qB = qtB * 64 + w * 16 + lr;
        #pragma unroll
        for (int dh = 0; dh < 2; ++dh) {
            qfA[dh] = *(const half8*)&Qb[(size_t)qA * 64 + dh * 32 + lg * 8];
            qfB[dh] = *(const half8*)&Qb[(size_t)qB * 64 + dh * 32 + lg * 8];
            #pragma unroll
            for (int j = 0; j < 8; ++j) { qfA[dh][j] *= qsc; qfB[dh][j] *= qsc; }
        }
    }

    f32x4 accA[4] = {}, accB[4] = {};
    float mA = -1e30f, lA = 0.f, mB = -1e30f, lB = 0.f;
    int swq = lr & 7;
    int s0 = 0, cur = 0;

    auto STAGE = [&](int bsel, int s0s) {
        #pragma unroll
        for (int cc = 0; cc < 2; ++cc) {
            int base = w * 128 + cc * 64;
            int idx = base + lane;
            int row = idx >> 3;
            int cg = (idx & 7) ^ (row & 7);
            gload16(&Kb[(size_t)(s0s + row) * 64 + cg * 8], &Kt[bsel][base * 8]);
            gload16(&Vb[(size_t)row * S_ + s0s + cg * 8], &Vt[bsel][base * 8]);
        }
    };

    auto smax = [&](f32x4 (&z)[4], float& mrun, float& lrun, f32x4 (&acc)[4],
                    _Float16* plw, bool domask, int q0g, half8 (&pa)[2]) {
        int qw0 = q0g + w * 16;
        if (domask) {
            int q = qw0 + lr;
            #pragma unroll
            for (int nt = 0; nt < 4; ++nt)
                #pragma unroll
                for (int r = 0; r < 4; ++r) {
                    int kv = s0 + nt * 16 + lg * 4 + r;
                    if (kv > q) z[nt][r] = -1e30f;
                }
        }
        float mx = z[0][0];
        #pragma unroll
        for (int nt = 0; nt < 4; ++nt)
            #pragma unroll
            for (int r = 0; r < 4; ++r) mx = fmaxf(mx, z[nt][r]);
        mx = fmaxf(mx, __shfl_xor(mx, 16));
        mx = fmaxf(mx, __shfl_xor(mx, 32));

        if (!__all(mx <= mrun + 11.f)) {
            float mnew = fmaxf(mrun, mx);
            float fac = __builtin_amdgcn_exp2f(mrun - mnew);
            mrun = mnew;
            lrun *= fac;
            float facv[4];
            #pragma unroll
            for (int r = 0; r < 4; ++r) facv[r] = __shfl(fac, lg * 4 + r);
            #pragma unroll
            for (int dt = 0; dt < 4; ++dt)
                #pragma unroll
                for (int r = 0; r < 4; ++r) acc[dt][r] *= facv[r];
        }

        float rs = 0.f;
        #pragma unroll
        for (int nt = 0; nt < 4; ++nt)
            #pragma unroll
            for (int r = 0; r < 4; ++r) {
                float pv = __builtin_amdgcn_exp2f(z[nt][r] - mrun);
                z[nt][r] = pv;
                rs += pv;
            }
        rs += __shfl_xor(rs, 16);
        rs += __shfl_xor(rs, 32);
        lrun += rs;

        #pragma unroll
        for (int nt = 0; nt < 4; ++nt) {
            unsigned ua = __builtin_bit_cast(unsigned, __builtin_amdgcn_cvt_pkrtz(z[nt][0], z[nt][1]));
            unsigned ub = __builtin_bit_cast(unsigned, __builtin_amdgcn_cvt_pkrtz(z[nt][2], z[nt][3]));
            int chunk = 2 * nt + (lg >> 1);
            char* pp = (char*)plw + lr * 128 + ((chunk ^ swq) * 16) + (lg & 1) * 8;
            *(uint2*)pp = make_uint2(ua, ub);
        }
        #pragma unroll
        for (int hh = 0; hh < 2; ++hh)
            pa[hh] = *(const half8*)((const char*)plw + lr * 128 + (((4 * hh + lg) ^ swq) * 16));
    };

    STAGE(0, 0);
    for (int ti = 0; ti <= qtB; ++ti) {
        s0 = ti << 6;
        cur = ti & 1;
        __syncthreads();                  // tile ti resident
        if (ti < qtB) STAGE(cur ^ 1, s0 + 64);

        if (ti <= qtA) {
            f32x4 zB[4], zA[4];
            __builtin_amdgcn_s_setprio(1);
            #pragma unroll
            for (int nt = 0; nt < 4; ++nt) {
                int rr = nt * 16 + lr;
                half8 kf0 = *(const half8*)&Kt[cur][rr * 64 + ((lg ^ swq) * 8)];
                half8 kf1 = *(const half8*)&Kt[cur][rr * 64 + (((4 + lg) ^ swq) * 8)];
                f32x4 z = {0.f, 0.f, 0.f, 0.f};
                z = __builtin_amdgcn_mfma_f32_16x16x32_f16(kf0, qfB[0], z, 0, 0, 0);
                z = __builtin_amdgcn_mfma_f32_16x16x32_f16(kf1, qfB[1], z, 0, 0, 0);
                zB[nt] = z;
                f32x4 y = {0.f, 0.f, 0.f, 0.f};
                y = __builtin_amdgcn_mfma_f32_16x16x32_f16(kf0, qfA[0], y, 0, 0, 0);
                y = __builtin_amdgcn_mfma_f32_16x16x32_f16(kf1, qfA[1], y, 0, 0, 0);
                zA[nt] = y;
            }
            __builtin_amdgcn_s_setprio(0);
            half8 paB[2], paA[2];
            smax(zB, mB, lB, accB, &PlB[w][0], false, qtB * 64, paB);
            smax(zA, mA, lA, accA, &PlA[w][0], ti == qtA, qtA * 64, paA);
            __builtin_amdgcn_s_setprio(1);
            #pragma unroll
            for (int dt = 0; dt < 4; ++dt) {
                int vr = dt * 16 + lr;
                #pragma unroll
                for (int hh = 0; hh < 2; ++hh) {
                    half8 vb = *(const half8*)&Vt[cur][vr * 64 + (((4 * hh + lg) ^ swq) * 8)];
                    accB[dt] = __builtin_amdgcn_mfma_f32_16x16x32_f16(paB[hh], vb, accB[dt], 0, 0, 0);
                    accA[dt] = __builtin_amdgcn_mfma_f32_16x16x32_f16(paA[hh], vb, accA[dt], 0, 0, 0);
                }
            }
            __builtin_amdgcn_s_setprio(0);
        } else {
            f32x4 zB[4];
            __builtin_amdgcn_s_setprio(1);
            #pragma unroll
            for (int nt = 0; nt < 4; ++nt) {
                int rr = nt * 16 + lr;
                half8 kf0 = *(const half8*)&Kt[cur][rr * 64 + ((lg ^ swq) * 8)];
                half8 kf1 = *(const half8*)&Kt[cur][rr * 64 + (((4 + lg) ^ swq) * 8)];
                f32x4 z = {0.f, 0.f, 0.f, 0.f};
                z = __builtin_amdgcn_mfma_f32_16x16x32_f16(kf0, qfB[0], z, 0, 0, 0);
                z = __builtin_amdgcn_mfma_f32_16x16x32_f16(kf1, qfB[1], z, 0, 0, 0);
                zB[nt] = z;
            }
            __builtin_amdgcn_s_setprio(0);
            half8 paB[2];
            smax(zB, mB, lB, accB, &PlB[w][0], ti == qtB, qtB * 64, paB);
            __builtin_amdgcn_s_setprio(1);
            #pragma unroll
            for (int dt = 0; dt < 4; ++dt) {
                int vr = dt * 16 + lr;
                #pragma unroll
                for (int hh = 0; hh < 2; ++hh) {
                    half8 vb = *(const half8*)&Vt[cur][vr * 64 + (((4 * hh + lg) ^ swq) * 8)];
                    accB[dt] = __builtin_amdgcn_mfma_f32_16x16x32_f16(paB[hh], vb, accB[dt], 0, 0, 0);
                }
            }
            __builtin_amdgcn_s_setprio(0);
        }
    }

    int b = bh >> 4, h = bh & 15;
    auto writeout = [&](const f32x4* acc, float lrun, int q0g) {
        float linv[4];
        #pragma unroll
        for (int r = 0; r < 4; ++r) linv[r] = 1.0f / __shfl(lrun, lg * 4 + r);
        #pragma unroll
        for (int dt = 0; dt < 4; ++dt)
            #pragma unroll
            for (int r = 0; r < 4; ++r) {
                int s = q0g + w * 16 + lg * 4 + r;
                attn_out[((size_t)b * S_ + s) * HID_ + h * 64 + dt * 16 + lr] =
                    (_Float16)(acc[dt][r] * linv[r]);
            }
    };
    writeout(accB, lB, qtB * 64);
    writeout(accA, lA, qtA * 64);
}

// ---------------- launch ----------------

extern "C" void kernel_launch(void* const* d_in, const int* in_sizes, int n_in,
                              void* d_out, int out_size, void* d_ws, size_t ws_size,
                              hipStream_t stream) {
    const float* hidden  = (const float*)d_in[0];
    const float* w_qkv   = (const float*)d_in[1];
    const float* w_dense = (const float*)d_in[2];
    const float* b_dense = (const float*)d_in[3];
    float* out = (float*)d_out;
    char* ws = (char*)d_ws;

    _Float16* hh     = (_Float16*)(ws + 0);          // 8 MB; dead after QKV -> reused as attn_o
    _Float16* wqkvT  = (_Float16*)(ws + 8388608);    // 6 MB
    _Float16* wdT    = (_Float16*)(ws + 14680064);   // 2 MB
    float*    cos_t  = (float*)   (ws + 16777216);   // 256 KB
    float*    sin_t  = (float*)   (ws + 17039360);   // 256 KB
    _Float16* qh     = (_Float16*)(ws + 17301504);   // 8 MB [bh][s][d]
    _Float16* kh     = (_Float16*)(ws + 25690112);   // 8 MB [bh][s][d]
    _Float16* vt     = (_Float16*)(ws + 34078720);   // 8 MB [bh][d][s]
    _Float16* attn_o = hh;

    k_prep<<<6400, 256, 0, stream>>>(hidden, w_qkv, w_dense, hh, wqkvT, wdT, cos_t, sin_t);

    // QKV GEMM with fused RoPE/reshape epilogue (no fused buffer, no reshape kernel)
    k_gemm<false, true><<<(B_ * S_ / 128) * (3 * HID_ / 128), 256, 0, stream>>>(
        hh, wqkvT, nullptr, nullptr, B_ * S_, 3 * HID_, HID_, cos_t, sin_t, qh, kh, vt);

    k_attn<<<B_ * NH_ * (S_ / 64) / 2, 256, 0, stream>>>(qh, kh, vt, attn_o);

    k_gemm<true, false><<<(B_ * S_ / 128) * (HID_ / 128), 256, 0, stream>>>(
        attn_o, wdT, (void*)out, b_dense, B_ * S_, HID_, HID_,
        nullptr, nullptr, nullptr, nullptr, nullptr);
}